// Round 11
// baseline (702.843 us; speedup 1.0000x reference)
//
#include <hip/hip_runtime.h>
#include <math.h>

constexpr int BB = 8, NN = 2048, CC = 768, HH = 12, DD = 64;
constexpr float SCALE2 = 0.18033688011112042f;   // 0.125 * log2(e)
constexpr long long BNC = (long long)BB * NN * CC;   // 12,582,912
constexpr long long WN  = 589824LL;                  // 768*768
constexpr long long XN  = BNC;                       // x element count

using bf16x8  = __attribute__((ext_vector_type(8))) __bf16;
using floatx4 = __attribute__((ext_vector_type(4))) float;
using f16x4   = __attribute__((ext_vector_type(4))) _Float16;
using f16x8   = __attribute__((ext_vector_type(8))) _Float16;
using f16x2   = __attribute__((ext_vector_type(2))) _Float16;

static __device__ __forceinline__ unsigned short f2bf(float x) {
  unsigned u = __builtin_bit_cast(unsigned, x);
  u += 0x7fffu + ((u >> 16) & 1u);
  return (unsigned short)(u >> 16);
}
static __device__ __forceinline__ float bf2f(unsigned short s) {
  unsigned u = ((unsigned)s) << 16;
  return __builtin_bit_cast(float, u);
}

// v_cvt_pkrtz_f16_f32 wrapper: builtin returns __fp16-vector; bit_cast to our
// _Float16-based f16x2 (identical layout, incompatible C++ types — R9 fix).
static __device__ __forceinline__ f16x2 cvt_pk(float a, float b) {
  return __builtin_bit_cast(f16x2, __builtin_amdgcn_cvt_pkrtz(a, b));
}

static __device__ __forceinline__ void async_copy16(const unsigned short* g, unsigned short* l) {
  __builtin_amdgcn_global_load_lds(
      (const __attribute__((address_space(1))) unsigned int*)g,
      (__attribute__((address_space(3))) unsigned int*)l, 16, 0, 0);
}

// ---------------------------------------------------------------------------
// Convert pass: x -> bf16, wcat = concat(qw,kw,vw) bf16, owb = ow bf16,
// bcat = concat(qb,kb,vb) f32.
// ---------------------------------------------------------------------------
__global__ void convert_kernel(const float* __restrict__ x,
    const float* __restrict__ qw, const float* __restrict__ kw,
    const float* __restrict__ vw, const float* __restrict__ ow,
    const float* __restrict__ qb, const float* __restrict__ kb,
    const float* __restrict__ vb,
    unsigned short* __restrict__ xb, unsigned short* __restrict__ wcat,
    unsigned short* __restrict__ owb, float* __restrict__ bcat) {
  const long long gid = (long long)blockIdx.x * 256 + threadIdx.x;
  const long long off = gid * 4;
  if (off < XN + 4 * WN) {
    const float* s; unsigned short* d;
    if (off < XN)              { s = x  + off;                 d = xb   + off; }
    else if (off < XN + WN)    { s = qw + (off - XN);          d = wcat + (off - XN); }
    else if (off < XN + 2*WN)  { s = kw + (off - XN - WN);     d = wcat + (off - XN); }
    else if (off < XN + 3*WN)  { s = vw + (off - XN - 2*WN);   d = wcat + (off - XN); }
    else                       { s = ow + (off - XN - 3*WN);   d = owb  + (off - XN - 3*WN); }
    floatx4 v = *(const floatx4*)s;
    union { unsigned short us[4]; unsigned long long u; } pk;
    pk.us[0] = f2bf(v.x); pk.us[1] = f2bf(v.y); pk.us[2] = f2bf(v.z); pk.us[3] = f2bf(v.w);
    *(unsigned long long*)d = pk.u;
  } else {
    long long r = gid - (XN + 4 * WN) / 4;
    if (r < 576) {
      long long o2 = r * 4;
      const float* s = (o2 < 768) ? qb + o2 : (o2 < 1536) ? kb + (o2 - 768) : vb + (o2 - 1536);
      *(floatx4*)(bcat + o2) = *(const floatx4*)s;
    }
  }
}

// ---------------------------------------------------------------------------
// m97-style GEMM with XOR-swizzled LDS (R2 config: 128x128, 256 threads).
// OUT_MODE 0: QKV split (y:0-5 Q bf16, 6-11 K bf16, 12-17 V^T f16 PERMUTED
// per 128-key chunk: pos = quad*32 + nt*4 + r). OUT_MODE 1: f32 out.
// ---------------------------------------------------------------------------
template<int OUT_MODE>
__global__ __launch_bounds__(256, 3)
void gemm_m97(const unsigned short* __restrict__ A,
              const unsigned short* __restrict__ Bw,
              const float* __restrict__ bias,
              unsigned short* __restrict__ Qo,
              unsigned short* __restrict__ Ko,
              unsigned short* __restrict__ Vo,
              float* __restrict__ Fo) {
  __shared__ __align__(16) unsigned short As[128 * 64];
  __shared__ __align__(16) unsigned short Bs[128 * 64];
  const int t    = threadIdx.x;
  const int lane = t & 63;
  const int wv   = t >> 6;
  const int q    = lane >> 4;
  const int ml   = lane & 15;
  const int wm   = wv >> 1, wn = wv & 1;
  const int m0   = blockIdx.x * 128;
  const int n0   = blockIdx.y * 128;
  const int scol = ((lane & 7) ^ (lane >> 3)) * 8;   // swizzled source column

  const unsigned short* Ag = A  + (size_t)(m0 + wv * 32 + (lane >> 3)) * CC + scol;
  const unsigned short* Bg = Bw + (size_t)(n0 + wv * 32 + (lane >> 3)) * CC + scol;
  unsigned short* Al = As + (wv * 32) * 64;
  unsigned short* Bl = Bs + (wv * 32) * 64;

  floatx4 acc[4][4] = {};

  for (int k0 = 0; k0 < CC; k0 += 64) {
    #pragma unroll
    for (int i = 0; i < 4; ++i) {
      async_copy16(Ag + (size_t)i * 8 * CC + k0, Al + i * 8 * 64);
      async_copy16(Bg + (size_t)i * 8 * CC + k0, Bl + i * 8 * 64);
    }
    __syncthreads();
    #pragma unroll
    for (int kk = 0; kk < 2; ++kk) {
      bf16x8 af[4], bg[4];
      #pragma unroll
      for (int mt = 0; mt < 4; ++mt) {
        const int ch = ((kk * 4 + q) ^ (ml & 7)) * 8;
        af[mt] = *(const bf16x8*)&As[(wm * 64 + mt * 16 + ml) * 64 + ch];
      }
      #pragma unroll
      for (int nt = 0; nt < 4; ++nt) {
        const int ch = ((kk * 4 + q) ^ (ml & 7)) * 8;
        bg[nt] = *(const bf16x8*)&Bs[(wn * 64 + nt * 16 + ml) * 64 + ch];
      }
      #pragma unroll
      for (int mt = 0; mt < 4; ++mt)
        #pragma unroll
        for (int nt = 0; nt < 4; ++nt)
          acc[mt][nt] = __builtin_amdgcn_mfma_f32_16x16x32_bf16(af[mt], bg[nt], acc[mt][nt], 0, 0, 0);
    }
    __syncthreads();
  }

  #pragma unroll
  for (int nt = 0; nt < 4; ++nt) {
    const int col = n0 + wn * 64 + nt * 16 + ml;
    const float bv = bias[col];
    #pragma unroll
    for (int mt = 0; mt < 4; ++mt) {
      const int mbase = m0 + wm * 64 + mt * 16 + q * 4;
      if (OUT_MODE == 1) {
        #pragma unroll
        for (int r = 0; r < 4; ++r)
          Fo[(size_t)(mbase + r) * CC + col] = acc[mt][nt][r] + bv;
      } else {
        const int region = blockIdx.y / 6;            // 0=Q,1=K,2=V
        const int lc = col - region * CC;
        const int h = lc >> 6, hd = lc & 63;
        const int bidx = mbase >> 11;
        if (region == 2) {
          // permuted V^T f16: n' = (n&~127) + quad_*32 + nt_*4 + r
          const int nloc  = mbase & (NN - 1);
          const int pbase = (nloc & ~127) + (((nloc >> 2) & 3) << 5) + (((nloc >> 4) & 7) << 2);
          union { _Float16 h4[4]; unsigned long long u; } pk;
          #pragma unroll
          for (int r = 0; r < 4; ++r) pk.h4[r] = (_Float16)(acc[mt][nt][r] + bv);
          *(unsigned long long*)&Vo[((size_t)(bidx * HH + h) * DD + hd) * NN + pbase] = pk.u;
        } else {
          const int n = mbase & (NN - 1);
          unsigned short* o = (region == 0) ? Qo : Ko;
          #pragma unroll
          for (int r = 0; r < 4; ++r)
            o[((size_t)(bidx * HH + h) * NN + n + r) * DD + hd] = f2bf(acc[mt][nt][r] + bv);
        }
      }
    }
  }
}

// ---------------------------------------------------------------------------
// Flash attention v13 = v12 compute, 512-thread blocks (8 waves, QBLK=256).
// R10 post-mortem: pk-convert neutral (VALU 45.8->46.3%) — per-op VALU cuts
// exhausted; MFMA 52us + VALU 63us serialize at 2 waves/SIMD.
// v13 mechanism: merge qt-pairs -> (a) waves/SIMD 2->4 (2 blocks x 8 waves):
// cross-block phase diversity feeds both pipes; (b) same 16KB K + 16KB V
// tile serves 8 waves -> per-wave staging issue+addressing halves (part of
// the VALU pipe). Per-wave work unchanged (32 queries/wave — R8's QBLK
// shrink mistake not repeated). LDS 50KB x 2 blocks = 100KB/CU fits.
// launch_bounds(512,4): 4 waves/EU = 2 blocks/CU for B=512, VGPR cap 128.
// ---------------------------------------------------------------------------
__global__ __launch_bounds__(512, 4)
void attn_kernel(const unsigned short* __restrict__ Qp,
                 const unsigned short* __restrict__ Kp,
                 const unsigned short* __restrict__ Vt,   // f16, permuted
                 const float* __restrict__ sz,
                 unsigned short* __restrict__ attn_out) {
  __shared__ __align__(16) unsigned short Ks[2][128 * 64];   // bf16, swizzled (32KB)
  __shared__ __align__(16) unsigned short Vs[64 * 128];      // f16, permuted+swizzled (16KB)
  __shared__ __align__(16) float biasS[2][128];

  const int t    = threadIdx.x;
  const int lane = t & 63;
  const int wv   = t >> 6;                // 0..7
  const int q    = lane >> 4;
  const int ml   = lane & 15;
  // XCD swizzle: 768 blocks -> 96 contiguous wg per XCD; all 8 qt-blocks of
  // a bh share an XCD/L2.
  const int wg   = (blockIdx.x & 7) * 96 + (blockIdx.x >> 3);
  const int bh   = wg >> 3;               // 0..95
  const int qt   = wg & 7;                // 0..7 (256 queries per block)
  const int b    = bh / HH, h = bh % HH;
  const int qbase = qt * 256 + wv * 32;

  // Q B-frags: B[k=d=q*8+i][n=query=ml]
  bf16x8 qf[2][2];
  #pragma unroll
  for (int mq = 0; mq < 2; ++mq)
    #pragma unroll
    for (int kt = 0; kt < 2; ++kt)
      qf[mq][kt] = *(const bf16x8*)(Qp + ((size_t)bh * NN + qbase + mq * 16 + ml) * DD + kt * 32 + q * 8);

  floatx4 O[2][4] = {};     // O^T: row d = dt*16+quad*4+r, col query = mq*16+ml
  floatx4 Osum[2] = {};
  f16x8 vone8 = {(_Float16)1.f, (_Float16)1.f, (_Float16)1.f, (_Float16)1.f,
                 (_Float16)1.f, (_Float16)1.f, (_Float16)1.f, (_Float16)1.f};

  // K staging (512 threads, 2 copies x 64 rows): row r = t>>3 (+64i),
  // r&7 = (lane>>3)&7 -> source chunk swizzle identical to 256-thr version.
  const int kswz = ((lane & 7) ^ (lane >> 3)) * 8;
  // V staging (512 threads, 2 copies x 32 rows): row r = t>>4 (+32i),
  // r&7 = (lane>>4) | ((wv&1)<<2) -> per-wave-parity XOR key, i-independent.
  const int vswz = ((lane & 15) ^ ((lane >> 4) | ((wv & 1) << 2))) * 8;
  const unsigned short* Kg = Kp + ((size_t)bh * NN + (t >> 3)) * DD + kswz;
  const unsigned short* Vg = Vt + ((size_t)bh * DD + (t >> 4)) * NN;
  unsigned short* Kl0 = &Ks[0][(t >> 3) * 64];
  unsigned short* Kl1 = &Ks[1][(t >> 3) * 64];
  unsigned short* Vl  = Vs + (t >> 4) * 128;

  // ---- prologue: stage K[0] -> Ks[0], V[0] -> Vs; bias tile 0; sz for tile 1
  #pragma unroll
  for (int i = 0; i < 2; ++i) {
    async_copy16(Kg + (size_t)(i * 64) * DD, Kl0 + i * 64 * 64);
    async_copy16(Vg + (size_t)(i * 32) * NN + vswz, Vl + i * 32 * 128);
  }
  float szreg = 0.f;
  if (t < 128) {
    biasS[0][t] = log2f(sz[(size_t)b * NN + t]);
    szreg = sz[(size_t)b * NN + 128 + t];
  }
  __syncthreads();

  for (int jt = 0; jt < 16; ++jt) {
    const int cur = jt & 1;
    const int jn  = jt * 128 + 128;
    unsigned short* Kln = cur ? Kl0 : Kl1;

    // ---- top: issue K[t+1] async; publish bias[t+1] ----
    if (jt < 15) {
      #pragma unroll
      for (int i = 0; i < 2; ++i)
        async_copy16(Kg + (size_t)(jn + i * 64) * DD, Kln + i * 64 * 64);
      if (t < 128) {
        biasS[cur ^ 1][t] = log2f(szreg);             // value prefetched last iter
        int j2 = jn + 128; if (j2 + 128 > NN) j2 = NN - 128;
        szreg = sz[(size_t)b * NN + j2 + t];          // issue for tile jt+2
      }
    }

    // bias per key row: key-in-tile = nt*16 + quad*4 + r
    floatx4 bfr[8];
    #pragma unroll
    for (int nt = 0; nt < 8; ++nt)
      bfr[nt] = *(const floatx4*)&biasS[cur][nt * 16 + q * 4];

    // ---- S^T = K Q^T (swizzled chunk reads) ----
    floatx4 S[2][8];
    __builtin_amdgcn_s_setprio(1);
    #pragma unroll
    for (int nt = 0; nt < 8; ++nt) {
      const int ch0 = (q ^ (ml & 7)) * 8;
      const int ch1 = ((4 + q) ^ (ml & 7)) * 8;
      bf16x8 kf0 = *(const bf16x8*)&Ks[cur][(nt * 16 + ml) * 64 + ch0];
      bf16x8 kf1 = *(const bf16x8*)&Ks[cur][(nt * 16 + ml) * 64 + ch1];
      #pragma unroll
      for (int mq = 0; mq < 2; ++mq) {
        floatx4 a = {0.f, 0.f, 0.f, 0.f};
        a = __builtin_amdgcn_mfma_f32_16x16x32_bf16(kf0, qf[mq][0], a, 0, 0, 0);
        a = __builtin_amdgcn_mfma_f32_16x16x32_bf16(kf1, qf[mq][1], a, 0, 0, 0);
        S[mq][nt] = a;
      }
    }
    __builtin_amdgcn_s_setprio(0);

    // ---- p = exp2(s*SCALE2 + log2(size_k)); packed cvt into K=32 f16 frags.
    // slot j<4 <- nt=2tt (r=j); slot j>=4 <- nt=2tt+1 (r=j-4).
    f16x8 pfw[2][4];
    #pragma unroll
    for (int mq = 0; mq < 2; ++mq)
      #pragma unroll
      for (int tt = 0; tt < 4; ++tt) {
        float e[8];
        #pragma unroll
        for (int bb = 0; bb < 2; ++bb)
          #pragma unroll
          for (int r = 0; r < 4; ++r)
            e[bb * 4 + r] = __builtin_amdgcn_exp2f(fmaf(S[mq][2 * tt + bb][r], SCALE2, bfr[2 * tt + bb][r]));
        union { f16x2 h2[4]; f16x8 v; } pk;
        pk.h2[0] = cvt_pk(e[0], e[1]);
        pk.h2[1] = cvt_pk(e[2], e[3]);
        pk.h2[2] = cvt_pk(e[4], e[5]);
        pk.h2[3] = cvt_pk(e[6], e[7]);
        pfw[mq][tt] = pk.v;
      }

    // barrier Y: drains V[t] (issued last iter, covered by this tile's
    // QK^T+exp and earlier) and K[t+1] (issued above); syncs before PV.
    __syncthreads();

    // ---- O^T += V^T P^T (K=32 f16 MFMA; vv f16x8 IS the K=32 A-frag) ----
    __builtin_amdgcn_s_setprio(1);
    #pragma unroll
    for (int dt = 0; dt < 4; ++dt) {
      #pragma unroll
      for (int tt = 0; tt < 4; ++tt) {
        const int ch = ((q * 4 + tt) ^ (ml & 7)) * 8;
        f16x8 vv = *(const f16x8*)&Vs[(dt * 16 + ml) * 128 + ch];
        #pragma unroll
        for (int mq = 0; mq < 2; ++mq)
          O[mq][dt] = __builtin_amdgcn_mfma_f32_16x16x32_f16(vv, pfw[mq][tt], O[mq][dt], 0, 0, 0);
      }
    }
    __builtin_amdgcn_s_setprio(0);

    // barrier X: all PV reads of Vs complete -> safe to restage Vs
    __syncthreads();

    // ---- issue V[t+1] async (covered by Osum + next tile's QK^T+exp) ----
    if (jt < 15) {
      #pragma unroll
      for (int i = 0; i < 2; ++i)
        async_copy16(Vg + (size_t)(i * 32) * NN + jn + vswz, Vl + i * 32 * 128);
    }

    // ---- Osum += 1 * P^T (register-only; covers the V issue) ----
    __builtin_amdgcn_s_setprio(1);
    #pragma unroll
    for (int mq = 0; mq < 2; ++mq)
      #pragma unroll
      for (int tt = 0; tt < 4; ++tt)
        Osum[mq] = __builtin_amdgcn_mfma_f32_16x16x32_f16(vone8, pfw[mq][tt], Osum[mq], 0, 0, 0);
    __builtin_amdgcn_s_setprio(0);
  }

  // ---- epilogue: lane owns query = qbase+mq*16+ml, d = dt*16+quad*4+r ----
  #pragma unroll
  for (int mq = 0; mq < 2; ++mq) {
    const float linv = 1.0f / Osum[mq][0];
    const int query = qbase + mq * 16 + ml;
    #pragma unroll
    for (int dt = 0; dt < 4; ++dt) {
      union { unsigned short us[4]; unsigned long long u; } pk;
      #pragma unroll
      for (int r = 0; r < 4; ++r) pk.us[r] = f2bf(O[mq][dt][r] * linv);
      *(unsigned long long*)&attn_out[((size_t)b * NN + query) * CC + h * DD + dt * 16 + q * 4] = pk.u;
    }
  }
}

// ---------------------------------------------------------------------------
// k_mean[b,n,hd] = (1/H) sum_h K[b,h,n,hd]  — vectorized: 4 hd per thread.
// ---------------------------------------------------------------------------
__global__ void kmean_kernel(const unsigned short* __restrict__ Kp, float* __restrict__ o) {
  int idx = blockIdx.x * 256 + threadIdx.x;   // 262144 threads total
  int hd4 = (idx & 15) << 2;
  int n   = (idx >> 4) & (NN - 1);
  int b   = idx >> 15;
  float s0 = 0.f, s1 = 0.f, s2 = 0.f, s3 = 0.f;
  #pragma unroll
  for (int h = 0; h < HH; ++h) {
    ushort4 u = *(const ushort4*)&Kp[(((size_t)b * HH + h) * NN + n) * DD + hd4];
    s0 += bf2f(u.x); s1 += bf2f(u.y); s2 += bf2f(u.z); s3 += bf2f(u.w);
  }
  float4 r;
  r.x = s0 * (1.0f / 12.0f); r.y = s1 * (1.0f / 12.0f);
  r.z = s2 * (1.0f / 12.0f); r.w = s3 * (1.0f / 12.0f);
  *(float4*)&o[(size_t)idx * 4] = r;
}

extern "C" void kernel_launch(void* const* d_in, const int* in_sizes, int n_in,
                              void* d_out, int out_size, void* d_ws, size_t ws_size,
                              hipStream_t stream) {
  const float* x   = (const float*)d_in[0];
  const float* sz  = (const float*)d_in[1];
  const float* q_w = (const float*)d_in[2];
  const float* q_b = (const float*)d_in[3];
  const float* k_w = (const float*)d_in[4];
  const float* k_b = (const float*)d_in[5];
  const float* v_w = (const float*)d_in[6];
  const float* v_b = (const float*)d_in[7];
  const float* o_w = (const float*)d_in[8];
  const float* o_b = (const float*)d_in[9];

  float* out0  = (float*)d_out;              // [B,N,C] f32
  float* outKm = out0 + (size_t)BNC;         // [B,N,HD] f32

  unsigned short* xb   = (unsigned short*)d_ws;              // bf16 x / later Aw
  unsigned short* wcat = xb + XN;                            // bf16 [2304][768]
  unsigned short* owb  = wcat + 3 * WN;                      // bf16 [768][768]
  float*          bcat = (float*)(owb + WN);                 // f32 [2304]
  unsigned short* Qw   = (unsigned short*)(bcat + 2304);     // bf16 [B,H,N,64]
  unsigned short* Kw   = Qw + BNC;                           // bf16 [B,H,N,64]
  unsigned short* Vtw  = Kw + BNC;                           // f16  [B,H,64,N] permuted
  unsigned short* Aw   = xb;                                 // alias

  dim3 tb(256, 1, 1);
  convert_kernel<<<dim3(14595), tb, 0, stream>>>(x, q_w, k_w, v_w, o_w, q_b, k_b, v_b,
                                                 xb, wcat, owb, bcat);
  gemm_m97<0><<<dim3(128, 18), tb, 0, stream>>>(xb, wcat, bcat, Qw, Kw, Vtw, nullptr);
  attn_kernel<<<dim3(768), dim3(512, 1, 1), 0, stream>>>(Qw, Kw, Vtw, sz, Aw);
  gemm_m97<1><<<dim3(128, 6), tb, 0, stream>>>(Aw, owb, o_b, nullptr, nullptr, nullptr, out0);
  kmean_kernel<<<dim3(1024), tb, 0, stream>>>(Kw, outKm);
}

// Round 12
// 346.602 us; speedup vs baseline: 2.0278x; 2.0278x over previous
//
#include <hip/hip_runtime.h>
#include <math.h>

constexpr int BB = 8, NN = 2048, CC = 768, HH = 12, DD = 64;
constexpr float SCALE2 = 0.18033688011112042f;   // 0.125 * log2(e)
constexpr long long BNC = (long long)BB * NN * CC;   // 12,582,912
constexpr long long WN  = 589824LL;                  // 768*768
constexpr long long XN  = BNC;                       // x element count

using bf16x8  = __attribute__((ext_vector_type(8))) __bf16;
using floatx4 = __attribute__((ext_vector_type(4))) float;
using f16x4   = __attribute__((ext_vector_type(4))) _Float16;
using f16x8   = __attribute__((ext_vector_type(8))) _Float16;
using f16x2   = __attribute__((ext_vector_type(2))) _Float16;

static __device__ __forceinline__ unsigned short f2bf(float x) {
  unsigned u = __builtin_bit_cast(unsigned, x);
  u += 0x7fffu + ((u >> 16) & 1u);
  return (unsigned short)(u >> 16);
}
static __device__ __forceinline__ float bf2f(unsigned short s) {
  unsigned u = ((unsigned)s) << 16;
  return __builtin_bit_cast(float, u);
}

// v_cvt_pkrtz_f16_f32 wrapper (R9 fix: builtin returns __fp16-vector).
static __device__ __forceinline__ f16x2 cvt_pk(float a, float b) {
  return __builtin_bit_cast(f16x2, __builtin_amdgcn_cvt_pkrtz(a, b));
}

static __device__ __forceinline__ void async_copy16(const unsigned short* g, unsigned short* l) {
  __builtin_amdgcn_global_load_lds(
      (const __attribute__((address_space(1))) unsigned int*)g,
      (__attribute__((address_space(3))) unsigned int*)l, 16, 0, 0);
}

// ---------------------------------------------------------------------------
// Convert pass: x -> bf16, wcat = concat(qw,kw,vw) bf16, owb = ow bf16,
// bcat = concat(qb,kb,vb) f32.
// ---------------------------------------------------------------------------
__global__ void convert_kernel(const float* __restrict__ x,
    const float* __restrict__ qw, const float* __restrict__ kw,
    const float* __restrict__ vw, const float* __restrict__ ow,
    const float* __restrict__ qb, const float* __restrict__ kb,
    const float* __restrict__ vb,
    unsigned short* __restrict__ xb, unsigned short* __restrict__ wcat,
    unsigned short* __restrict__ owb, float* __restrict__ bcat) {
  const long long gid = (long long)blockIdx.x * 256 + threadIdx.x;
  const long long off = gid * 4;
  if (off < XN + 4 * WN) {
    const float* s; unsigned short* d;
    if (off < XN)              { s = x  + off;                 d = xb   + off; }
    else if (off < XN + WN)    { s = qw + (off - XN);          d = wcat + (off - XN); }
    else if (off < XN + 2*WN)  { s = kw + (off - XN - WN);     d = wcat + (off - XN); }
    else if (off < XN + 3*WN)  { s = vw + (off - XN - 2*WN);   d = wcat + (off - XN); }
    else                       { s = ow + (off - XN - 3*WN);   d = owb  + (off - XN - 3*WN); }
    floatx4 v = *(const floatx4*)s;
    union { unsigned short us[4]; unsigned long long u; } pk;
    pk.us[0] = f2bf(v.x); pk.us[1] = f2bf(v.y); pk.us[2] = f2bf(v.z); pk.us[3] = f2bf(v.w);
    *(unsigned long long*)d = pk.u;
  } else {
    long long r = gid - (XN + 4 * WN) / 4;
    if (r < 576) {
      long long o2 = r * 4;
      const float* s = (o2 < 768) ? qb + o2 : (o2 < 1536) ? kb + (o2 - 768) : vb + (o2 - 1536);
      *(floatx4*)(bcat + o2) = *(const floatx4*)s;
    }
  }
}

// ---------------------------------------------------------------------------
// m97-style GEMM, R12: BM=128 x BN=256, 512 threads (8 waves, 2x4 grid).
// Halves A-panel refetch (QKV 18->9 panels: 432->216 MB; out-proj 6->3).
// R3 ran this shape with launch_bounds(512,4) -> VGPR cap 512/(2*4)=64 ->
// acc[4][4] alone spilled (the "BN=256 regression" was the spill, not the
// shape). (512,2): cap 128 >= ~116 needed; k = 2*4/8 = 1 block/CU = 8 waves
// = 2 waves/SIMD, same residency as the 128^2 config.
// OUT_MODE 0: QKV split (y:0-2 Q, 3-5 K, 6-8 V^T f16 PERMUTED per 128-key
// chunk: pos = quad*32 + nt*4 + r). OUT_MODE 1: f32 out.
// ---------------------------------------------------------------------------
template<int OUT_MODE>
__global__ __launch_bounds__(512, 2)
void gemm_m97(const unsigned short* __restrict__ A,
              const unsigned short* __restrict__ Bw,
              const float* __restrict__ bias,
              unsigned short* __restrict__ Qo,
              unsigned short* __restrict__ Ko,
              unsigned short* __restrict__ Vo,
              float* __restrict__ Fo) {
  __shared__ __align__(16) unsigned short As[128 * 64];
  __shared__ __align__(16) unsigned short Bs[256 * 64];
  const int t    = threadIdx.x;
  const int lane = t & 63;
  const int wv   = t >> 6;                 // 0..7
  const int q    = lane >> 4;
  const int ml   = lane & 15;
  const int wm   = wv >> 2, wn = wv & 3;   // 2 x 4 wave grid
  const int m0   = blockIdx.x * 128;
  const int n0   = blockIdx.y * 256;
  const int scol = ((lane & 7) ^ (lane >> 3)) * 8;   // swizzled source column

  const unsigned short* Ag = A  + (size_t)(m0 + wv * 16 + (lane >> 3)) * CC + scol;
  const unsigned short* Bg = Bw + (size_t)(n0 + wv * 32 + (lane >> 3)) * CC + scol;
  unsigned short* Al = As + (wv * 16) * 64;
  unsigned short* Bl = Bs + (wv * 32) * 64;

  floatx4 acc[4][4] = {};

  for (int k0 = 0; k0 < CC; k0 += 64) {
    #pragma unroll
    for (int i = 0; i < 2; ++i)
      async_copy16(Ag + (size_t)i * 8 * CC + k0, Al + i * 8 * 64);
    #pragma unroll
    for (int i = 0; i < 4; ++i)
      async_copy16(Bg + (size_t)i * 8 * CC + k0, Bl + i * 8 * 64);
    __syncthreads();
    #pragma unroll
    for (int kk = 0; kk < 2; ++kk) {
      bf16x8 af[4], bg[4];
      #pragma unroll
      for (int mt = 0; mt < 4; ++mt) {
        const int ch = ((kk * 4 + q) ^ (ml & 7)) * 8;
        af[mt] = *(const bf16x8*)&As[(wm * 64 + mt * 16 + ml) * 64 + ch];
      }
      #pragma unroll
      for (int nt = 0; nt < 4; ++nt) {
        const int ch = ((kk * 4 + q) ^ (ml & 7)) * 8;
        bg[nt] = *(const bf16x8*)&Bs[(wn * 64 + nt * 16 + ml) * 64 + ch];
      }
      #pragma unroll
      for (int mt = 0; mt < 4; ++mt)
        #pragma unroll
        for (int nt = 0; nt < 4; ++nt)
          acc[mt][nt] = __builtin_amdgcn_mfma_f32_16x16x32_bf16(af[mt], bg[nt], acc[mt][nt], 0, 0, 0);
    }
    __syncthreads();
  }

  #pragma unroll
  for (int nt = 0; nt < 4; ++nt) {
    const int col = n0 + wn * 64 + nt * 16 + ml;
    const float bv = bias[col];
    #pragma unroll
    for (int mt = 0; mt < 4; ++mt) {
      const int mbase = m0 + wm * 64 + mt * 16 + q * 4;
      if (OUT_MODE == 1) {
        #pragma unroll
        for (int r = 0; r < 4; ++r)
          Fo[(size_t)(mbase + r) * CC + col] = acc[mt][nt][r] + bv;
      } else {
        const int region = blockIdx.y / 3;            // 0=Q,1=K,2=V (256-wide panels)
        const int lc = col - region * CC;
        const int h = lc >> 6, hd = lc & 63;
        const int bidx = mbase >> 11;
        if (region == 2) {
          // permuted V^T f16: n' = (n&~127) + quad_*32 + nt_*4 + r
          const int nloc  = mbase & (NN - 1);
          const int pbase = (nloc & ~127) + (((nloc >> 2) & 3) << 5) + (((nloc >> 4) & 7) << 2);
          union { _Float16 h4[4]; unsigned long long u; } pk;
          #pragma unroll
          for (int r = 0; r < 4; ++r) pk.h4[r] = (_Float16)(acc[mt][nt][r] + bv);
          *(unsigned long long*)&Vo[((size_t)(bidx * HH + h) * DD + hd) * NN + pbase] = pk.u;
        } else {
          const int n = mbase & (NN - 1);
          unsigned short* o = (region == 0) ? Qo : Ko;
          #pragma unroll
          for (int r = 0; r < 4; ++r)
            o[((size_t)(bidx * HH + h) * NN + n + r) * DD + hd] = f2bf(acc[mt][nt][r] + bv);
        }
      }
    }
  }
}

// ---------------------------------------------------------------------------
// Flash attention v12 (reverted exactly — best: 136.3us, R10).
// R11 post-mortem: (512,4) capped VGPR at 512/(2*4)=64 (my own R7 model,
// misapplied in R10 as "128") -> total spill, 505us. 256-thread (256,2)
// restored; the 512-thread merge would need arg=2 (cap 128) but then only
// 1 block/CU -> no diversity gain; abandoned.
// ---------------------------------------------------------------------------
__global__ __launch_bounds__(256, 2)
void attn_kernel(const unsigned short* __restrict__ Qp,
                 const unsigned short* __restrict__ Kp,
                 const unsigned short* __restrict__ Vt,   // f16, permuted
                 const float* __restrict__ sz,
                 unsigned short* __restrict__ attn_out) {
  __shared__ __align__(16) unsigned short Ks[2][128 * 64];   // bf16, swizzled (32KB)
  __shared__ __align__(16) unsigned short Vs[64 * 128];      // f16, permuted+swizzled (16KB)
  __shared__ __align__(16) float biasS[2][128];

  const int t    = threadIdx.x;
  const int lane = t & 63;
  const int wv   = t >> 6;
  const int q    = lane >> 4;
  const int ml   = lane & 15;
  // XCD swizzle: all 16 qt-blocks of a bh share an XCD/L2.
  const int wg   = (blockIdx.x & 7) * 192 + (blockIdx.x >> 3);
  const int bh   = wg >> 4;               // 0..95
  const int qt   = wg & 15;
  const int b    = bh / HH, h = bh % HH;
  const int qbase = qt * 128 + wv * 32;

  // Q B-frags: B[k=d=q*8+i][n=query=ml]
  bf16x8 qf[2][2];
  #pragma unroll
  for (int mq = 0; mq < 2; ++mq)
    #pragma unroll
    for (int kt = 0; kt < 2; ++kt)
      qf[mq][kt] = *(const bf16x8*)(Qp + ((size_t)bh * NN + qbase + mq * 16 + ml) * DD + kt * 32 + q * 8);

  floatx4 O[2][4] = {};     // O^T: row d = dt*16+quad*4+r, col query = mq*16+ml
  floatx4 Osum[2] = {};
  f16x8 vone8 = {(_Float16)1.f, (_Float16)1.f, (_Float16)1.f, (_Float16)1.f,
                 (_Float16)1.f, (_Float16)1.f, (_Float16)1.f, (_Float16)1.f};

  const int kswz = ((lane & 7) ^ (lane >> 3)) * 8;        // K staging column
  const int vswz = ((lane & 15) ^ (lane >> 4)) * 8;       // V staging column (i even)
  const unsigned short* Kg = Kp + ((size_t)bh * NN + wv * 32 + (lane >> 3)) * DD + kswz;
  const unsigned short* Vg = Vt + ((size_t)bh * DD + wv * 16 + (lane >> 4)) * NN;
  unsigned short* Kl0 = &Ks[0][(wv * 32) * 64];
  unsigned short* Kl1 = &Ks[1][(wv * 32) * 64];
  unsigned short* Vl  = Vs + (wv * 16) * 128;

  // ---- prologue: stage K[0] -> Ks[0], V[0] -> Vs; bias tile 0; sz for tile 1
  #pragma unroll
  for (int i = 0; i < 4; ++i) {
    async_copy16(Kg + (size_t)(i * 8) * DD, Kl0 + i * 8 * 64);
    async_copy16(Vg + (size_t)(i * 4) * NN + (vswz ^ ((i & 1) << 5)), Vl + i * 4 * 128);
  }
  float szreg = 0.f;
  if (t < 128) {
    biasS[0][t] = log2f(sz[(size_t)b * NN + t]);
    szreg = sz[(size_t)b * NN + 128 + t];
  }
  __syncthreads();

  for (int jt = 0; jt < 16; ++jt) {
    const int cur = jt & 1;
    const int jn  = jt * 128 + 128;
    unsigned short* Kln = cur ? Kl0 : Kl1;

    // ---- top: issue K[t+1] async; publish bias[t+1] ----
    if (jt < 15) {
      #pragma unroll
      for (int i = 0; i < 4; ++i)
        async_copy16(Kg + (size_t)(jn + i * 8) * DD, Kln + i * 8 * 64);
      if (t < 128) {
        biasS[cur ^ 1][t] = log2f(szreg);             // value prefetched last iter
        int j2 = jn + 128; if (j2 + 128 > NN) j2 = NN - 128;
        szreg = sz[(size_t)b * NN + j2 + t];          // issue for tile jt+2
      }
    }

    // bias per key row: key-in-tile = nt*16 + quad*4 + r
    floatx4 bfr[8];
    #pragma unroll
    for (int nt = 0; nt < 8; ++nt)
      bfr[nt] = *(const floatx4*)&biasS[cur][nt * 16 + q * 4];

    // ---- S^T = K Q^T (swizzled chunk reads) ----
    floatx4 S[2][8];
    __builtin_amdgcn_s_setprio(1);
    #pragma unroll
    for (int nt = 0; nt < 8; ++nt) {
      const int ch0 = (q ^ (ml & 7)) * 8;
      const int ch1 = ((4 + q) ^ (ml & 7)) * 8;
      bf16x8 kf0 = *(const bf16x8*)&Ks[cur][(nt * 16 + ml) * 64 + ch0];
      bf16x8 kf1 = *(const bf16x8*)&Ks[cur][(nt * 16 + ml) * 64 + ch1];
      #pragma unroll
      for (int mq = 0; mq < 2; ++mq) {
        floatx4 a = {0.f, 0.f, 0.f, 0.f};
        a = __builtin_amdgcn_mfma_f32_16x16x32_bf16(kf0, qf[mq][0], a, 0, 0, 0);
        a = __builtin_amdgcn_mfma_f32_16x16x32_bf16(kf1, qf[mq][1], a, 0, 0, 0);
        S[mq][nt] = a;
      }
    }
    __builtin_amdgcn_s_setprio(0);

    // ---- p = exp2(s*SCALE2 + log2(size_k)); packed cvt into K=32 f16 frags.
    // slot j<4 <- nt=2tt (r=j); slot j>=4 <- nt=2tt+1 (r=j-4).
    f16x8 pfw[2][4];
    #pragma unroll
    for (int mq = 0; mq < 2; ++mq)
      #pragma unroll
      for (int tt = 0; tt < 4; ++tt) {
        float e[8];
        #pragma unroll
        for (int bb = 0; bb < 2; ++bb)
          #pragma unroll
          for (int r = 0; r < 4; ++r)
            e[bb * 4 + r] = __builtin_amdgcn_exp2f(fmaf(S[mq][2 * tt + bb][r], SCALE2, bfr[2 * tt + bb][r]));
        union { f16x2 h2[4]; f16x8 v; } pk;
        pk.h2[0] = cvt_pk(e[0], e[1]);
        pk.h2[1] = cvt_pk(e[2], e[3]);
        pk.h2[2] = cvt_pk(e[4], e[5]);
        pk.h2[3] = cvt_pk(e[6], e[7]);
        pfw[mq][tt] = pk.v;
      }

    // barrier Y: drains V[t] (issued last iter, covered by this tile's
    // QK^T+exp and earlier) and K[t+1] (issued above); syncs before PV.
    __syncthreads();

    // ---- O^T += V^T P^T (K=32 f16 MFMA; vv f16x8 IS the K=32 A-frag) ----
    __builtin_amdgcn_s_setprio(1);
    #pragma unroll
    for (int dt = 0; dt < 4; ++dt) {
      #pragma unroll
      for (int tt = 0; tt < 4; ++tt) {
        const int ch = ((q * 4 + tt) ^ (ml & 7)) * 8;
        f16x8 vv = *(const f16x8*)&Vs[(dt * 16 + ml) * 128 + ch];
        #pragma unroll
        for (int mq = 0; mq < 2; ++mq)
          O[mq][dt] = __builtin_amdgcn_mfma_f32_16x16x32_f16(vv, pfw[mq][tt], O[mq][dt], 0, 0, 0);
      }
    }
    __builtin_amdgcn_s_setprio(0);

    // barrier X: all PV reads of Vs complete -> safe to restage Vs
    __syncthreads();

    // ---- issue V[t+1] async (covered by Osum + next tile's QK^T+exp) ----
    if (jt < 15) {
      #pragma unroll
      for (int i = 0; i < 4; ++i)
        async_copy16(Vg + (size_t)(i * 4) * NN + jn + (vswz ^ ((i & 1) << 5)), Vl + i * 4 * 128);
    }

    // ---- Osum += 1 * P^T (register-only; covers the V issue) ----
    __builtin_amdgcn_s_setprio(1);
    #pragma unroll
    for (int mq = 0; mq < 2; ++mq)
      #pragma unroll
      for (int tt = 0; tt < 4; ++tt)
        Osum[mq] = __builtin_amdgcn_mfma_f32_16x16x32_f16(vone8, pfw[mq][tt], Osum[mq], 0, 0, 0);
    __builtin_amdgcn_s_setprio(0);
  }

  // ---- epilogue: lane owns query = qbase+mq*16+ml, d = dt*16+quad*4+r ----
  #pragma unroll
  for (int mq = 0; mq < 2; ++mq) {
    const float linv = 1.0f / Osum[mq][0];
    const int query = qbase + mq * 16 + ml;
    #pragma unroll
    for (int dt = 0; dt < 4; ++dt) {
      union { unsigned short us[4]; unsigned long long u; } pk;
      #pragma unroll
      for (int r = 0; r < 4; ++r) pk.us[r] = f2bf(O[mq][dt][r] * linv);
      *(unsigned long long*)&attn_out[((size_t)b * NN + query) * CC + h * DD + dt * 16 + q * 4] = pk.u;
    }
  }
}

// ---------------------------------------------------------------------------
// k_mean[b,n,hd] = (1/H) sum_h K[b,h,n,hd]  — vectorized: 4 hd per thread.
// ---------------------------------------------------------------------------
__global__ void kmean_kernel(const unsigned short* __restrict__ Kp, float* __restrict__ o) {
  int idx = blockIdx.x * 256 + threadIdx.x;   // 262144 threads total
  int hd4 = (idx & 15) << 2;
  int n   = (idx >> 4) & (NN - 1);
  int b   = idx >> 15;
  float s0 = 0.f, s1 = 0.f, s2 = 0.f, s3 = 0.f;
  #pragma unroll
  for (int h = 0; h < HH; ++h) {
    ushort4 u = *(const ushort4*)&Kp[(((size_t)b * HH + h) * NN + n) * DD + hd4];
    s0 += bf2f(u.x); s1 += bf2f(u.y); s2 += bf2f(u.z); s3 += bf2f(u.w);
  }
  float4 r;
  r.x = s0 * (1.0f / 12.0f); r.y = s1 * (1.0f / 12.0f);
  r.z = s2 * (1.0f / 12.0f); r.w = s3 * (1.0f / 12.0f);
  *(float4*)&o[(size_t)idx * 4] = r;
}

extern "C" void kernel_launch(void* const* d_in, const int* in_sizes, int n_in,
                              void* d_out, int out_size, void* d_ws, size_t ws_size,
                              hipStream_t stream) {
  const float* x   = (const float*)d_in[0];
  const float* sz  = (const float*)d_in[1];
  const float* q_w = (const float*)d_in[2];
  const float* q_b = (const float*)d_in[3];
  const float* k_w = (const float*)d_in[4];
  const float* k_b = (const float*)d_in[5];
  const float* v_w = (const float*)d_in[6];
  const float* v_b = (const float*)d_in[7];
  const float* o_w = (const float*)d_in[8];
  const float* o_b = (const float*)d_in[9];

  float* out0  = (float*)d_out;              // [B,N,C] f32
  float* outKm = out0 + (size_t)BNC;         // [B,N,HD] f32

  unsigned short* xb   = (unsigned short*)d_ws;              // bf16 x / later Aw
  unsigned short* wcat = xb + XN;                            // bf16 [2304][768]
  unsigned short* owb  = wcat + 3 * WN;                      // bf16 [768][768]
  float*          bcat = (float*)(owb + WN);                 // f32 [2304]
  unsigned short* Qw   = (unsigned short*)(bcat + 2304);     // bf16 [B,H,N,64]
  unsigned short* Kw   = Qw + BNC;                           // bf16 [B,H,N,64]
  unsigned short* Vtw  = Kw + BNC;                           // f16  [B,H,64,N] permuted
  unsigned short* Aw   = xb;                                 // alias

  dim3 tb(256, 1, 1);
  dim3 tg(512, 1, 1);
  convert_kernel<<<dim3(14595), tb, 0, stream>>>(x, q_w, k_w, v_w, o_w, q_b, k_b, v_b,
                                                 xb, wcat, owb, bcat);
  gemm_m97<0><<<dim3(128, 9), tg, 0, stream>>>(xb, wcat, bcat, Qw, Kw, Vtw, nullptr);
  attn_kernel<<<dim3(BB * HH * 16), tb, 0, stream>>>(Qw, Kw, Vtw, sz, Aw);
  gemm_m97<1><<<dim3(128, 3), tg, 0, stream>>>(Aw, owb, o_b, nullptr, nullptr, nullptr, out0);
  kmean_kernel<<<dim3(1024), tb, 0, stream>>>(Kw, outKm);
}

// Round 13
// 336.777 us; speedup vs baseline: 2.0870x; 1.0292x over previous
//
#include <hip/hip_runtime.h>
#include <math.h>

constexpr int BB = 8, NN = 2048, CC = 768, HH = 12, DD = 64;
constexpr float SCALE2 = 0.18033688011112042f;   // 0.125 * log2(e)
constexpr long long BNC = (long long)BB * NN * CC;   // 12,582,912
constexpr long long WN  = 589824LL;                  // 768*768
constexpr long long XN  = BNC;                       // x element count

using bf16x8  = __attribute__((ext_vector_type(8))) __bf16;
using floatx4 = __attribute__((ext_vector_type(4))) float;
using f16x4   = __attribute__((ext_vector_type(4))) _Float16;
using f16x8   = __attribute__((ext_vector_type(8))) _Float16;
using f16x2   = __attribute__((ext_vector_type(2))) _Float16;

static __device__ __forceinline__ unsigned short f2bf(float x) {
  unsigned u = __builtin_bit_cast(unsigned, x);
  u += 0x7fffu + ((u >> 16) & 1u);
  return (unsigned short)(u >> 16);
}
static __device__ __forceinline__ float bf2f(unsigned short s) {
  unsigned u = ((unsigned)s) << 16;
  return __builtin_bit_cast(float, u);
}

// v_cvt_pkrtz_f16_f32 wrapper (R9 fix: builtin returns __fp16-vector).
static __device__ __forceinline__ f16x2 cvt_pk(float a, float b) {
  return __builtin_bit_cast(f16x2, __builtin_amdgcn_cvt_pkrtz(a, b));
}

static __device__ __forceinline__ void async_copy16(const unsigned short* g, unsigned short* l) {
  __builtin_amdgcn_global_load_lds(
      (const __attribute__((address_space(1))) unsigned int*)g,
      (__attribute__((address_space(3))) unsigned int*)l, 16, 0, 0);
}

// ---------------------------------------------------------------------------
// Convert pass: x -> bf16, wcat = concat(qw,kw,vw) bf16, owb = ow bf16,
// bcat = concat(qb,kb,vb) f32.
// ---------------------------------------------------------------------------
__global__ void convert_kernel(const float* __restrict__ x,
    const float* __restrict__ qw, const float* __restrict__ kw,
    const float* __restrict__ vw, const float* __restrict__ ow,
    const float* __restrict__ qb, const float* __restrict__ kb,
    const float* __restrict__ vb,
    unsigned short* __restrict__ xb, unsigned short* __restrict__ wcat,
    unsigned short* __restrict__ owb, float* __restrict__ bcat) {
  const long long gid = (long long)blockIdx.x * 256 + threadIdx.x;
  const long long off = gid * 4;
  if (off < XN + 4 * WN) {
    const float* s; unsigned short* d;
    if (off < XN)              { s = x  + off;                 d = xb   + off; }
    else if (off < XN + WN)    { s = qw + (off - XN);          d = wcat + (off - XN); }
    else if (off < XN + 2*WN)  { s = kw + (off - XN - WN);     d = wcat + (off - XN); }
    else if (off < XN + 3*WN)  { s = vw + (off - XN - 2*WN);   d = wcat + (off - XN); }
    else                       { s = ow + (off - XN - 3*WN);   d = owb  + (off - XN - 3*WN); }
    floatx4 v = *(const floatx4*)s;
    union { unsigned short us[4]; unsigned long long u; } pk;
    pk.us[0] = f2bf(v.x); pk.us[1] = f2bf(v.y); pk.us[2] = f2bf(v.z); pk.us[3] = f2bf(v.w);
    *(unsigned long long*)d = pk.u;
  } else {
    long long r = gid - (XN + 4 * WN) / 4;
    if (r < 576) {
      long long o2 = r * 4;
      const float* s = (o2 < 768) ? qb + o2 : (o2 < 1536) ? kb + (o2 - 768) : vb + (o2 - 1536);
      *(floatx4*)(bcat + o2) = *(const floatx4*)s;
    }
  }
}

// ---------------------------------------------------------------------------
// m97-style GEMM with XOR-swizzled LDS (128x128, 256 threads, (256,3) —
// FINAL: BN=256 tested clean at (512,2) in R12, neutral-to-worse; 128^2's
// 3 blocks/CU staging overlap wins).
// OUT_MODE 0: QKV split (y:0-5 Q bf16, 6-11 K bf16, 12-17 V^T f16 PERMUTED
// per 128-key chunk: pos = quad*32 + nt*4 + r). OUT_MODE 1: f32 out.
// ---------------------------------------------------------------------------
template<int OUT_MODE>
__global__ __launch_bounds__(256, 3)
void gemm_m97(const unsigned short* __restrict__ A,
              const unsigned short* __restrict__ Bw,
              const float* __restrict__ bias,
              unsigned short* __restrict__ Qo,
              unsigned short* __restrict__ Ko,
              unsigned short* __restrict__ Vo,
              float* __restrict__ Fo) {
  __shared__ __align__(16) unsigned short As[128 * 64];
  __shared__ __align__(16) unsigned short Bs[128 * 64];
  const int t    = threadIdx.x;
  const int lane = t & 63;
  const int wv   = t >> 6;
  const int q    = lane >> 4;
  const int ml   = lane & 15;
  const int wm   = wv >> 1, wn = wv & 1;
  const int m0   = blockIdx.x * 128;
  const int n0   = blockIdx.y * 128;
  const int scol = ((lane & 7) ^ (lane >> 3)) * 8;   // swizzled source column

  const unsigned short* Ag = A  + (size_t)(m0 + wv * 32 + (lane >> 3)) * CC + scol;
  const unsigned short* Bg = Bw + (size_t)(n0 + wv * 32 + (lane >> 3)) * CC + scol;
  unsigned short* Al = As + (wv * 32) * 64;
  unsigned short* Bl = Bs + (wv * 32) * 64;

  floatx4 acc[4][4] = {};

  for (int k0 = 0; k0 < CC; k0 += 64) {
    #pragma unroll
    for (int i = 0; i < 4; ++i) {
      async_copy16(Ag + (size_t)i * 8 * CC + k0, Al + i * 8 * 64);
      async_copy16(Bg + (size_t)i * 8 * CC + k0, Bl + i * 8 * 64);
    }
    __syncthreads();
    #pragma unroll
    for (int kk = 0; kk < 2; ++kk) {
      bf16x8 af[4], bg[4];
      #pragma unroll
      for (int mt = 0; mt < 4; ++mt) {
        const int ch = ((kk * 4 + q) ^ (ml & 7)) * 8;
        af[mt] = *(const bf16x8*)&As[(wm * 64 + mt * 16 + ml) * 64 + ch];
      }
      #pragma unroll
      for (int nt = 0; nt < 4; ++nt) {
        const int ch = ((kk * 4 + q) ^ (ml & 7)) * 8;
        bg[nt] = *(const bf16x8*)&Bs[(wn * 64 + nt * 16 + ml) * 64 + ch];
      }
      #pragma unroll
      for (int mt = 0; mt < 4; ++mt)
        #pragma unroll
        for (int nt = 0; nt < 4; ++nt)
          acc[mt][nt] = __builtin_amdgcn_mfma_f32_16x16x32_bf16(af[mt], bg[nt], acc[mt][nt], 0, 0, 0);
    }
    __syncthreads();
  }

  #pragma unroll
  for (int nt = 0; nt < 4; ++nt) {
    const int col = n0 + wn * 64 + nt * 16 + ml;
    const float bv = bias[col];
    #pragma unroll
    for (int mt = 0; mt < 4; ++mt) {
      const int mbase = m0 + wm * 64 + mt * 16 + q * 4;
      if (OUT_MODE == 1) {
        #pragma unroll
        for (int r = 0; r < 4; ++r)
          Fo[(size_t)(mbase + r) * CC + col] = acc[mt][nt][r] + bv;
      } else {
        const int region = blockIdx.y / 6;            // 0=Q,1=K,2=V
        const int lc = col - region * CC;
        const int h = lc >> 6, hd = lc & 63;
        const int bidx = mbase >> 11;
        if (region == 2) {
          // permuted V^T f16: n' = (n&~127) + quad_*32 + nt_*4 + r
          const int nloc  = mbase & (NN - 1);
          const int pbase = (nloc & ~127) + (((nloc >> 2) & 3) << 5) + (((nloc >> 4) & 7) << 2);
          union { _Float16 h4[4]; unsigned long long u; } pk;
          #pragma unroll
          for (int r = 0; r < 4; ++r) pk.h4[r] = (_Float16)(acc[mt][nt][r] + bv);
          *(unsigned long long*)&Vo[((size_t)(bidx * HH + h) * DD + hd) * NN + pbase] = pk.u;
        } else {
          const int n = mbase & (NN - 1);
          unsigned short* o = (region == 0) ? Qo : Ko;
          #pragma unroll
          for (int r = 0; r < 4; ++r)
            o[((size_t)(bidx * HH + h) * NN + n + r) * DD + hd] = f2bf(acc[mt][nt][r] + bv);
        }
      }
    }
  }
}

// ---------------------------------------------------------------------------
// Flash attention v14 = v12 + software-pipelined S/exp.
// Diagnosis (stable across R6/R10/R12): MFMA 52us + VALU 63us ~= 85% of the
// 134.5us wall -> pipes serialize. R11 killed the occupancy route (VGPR cap
// = 512/(2*arg)); the remaining overlap is INTRA-wave dual-issue.
// v14: interleave at source — per nt, issue the 4 QK^T MFMAs, then run the
// exp/cvt for nt-1 (inputs completed an iteration ago, independent of the
// in-flight MFMAs). Removes the setprio region-boundary between S and exp.
// Bonus: S liveness 64->16 VGPRs, bfr preload (32 regs) -> per-nt LDS read.
// P stored as f16x4 pf4[2][8]; K=32 B-frags formed by free register-pair
// shufflevector. Same math, same slots, identical numerics.
// ---------------------------------------------------------------------------
__global__ __launch_bounds__(256, 2)
void attn_kernel(const unsigned short* __restrict__ Qp,
                 const unsigned short* __restrict__ Kp,
                 const unsigned short* __restrict__ Vt,   // f16, permuted
                 const float* __restrict__ sz,
                 unsigned short* __restrict__ attn_out) {
  __shared__ __align__(16) unsigned short Ks[2][128 * 64];   // bf16, swizzled (32KB)
  __shared__ __align__(16) unsigned short Vs[64 * 128];      // f16, permuted+swizzled (16KB)
  __shared__ __align__(16) float biasS[2][128];

  const int t    = threadIdx.x;
  const int lane = t & 63;
  const int wv   = t >> 6;
  const int q    = lane >> 4;
  const int ml   = lane & 15;
  // XCD swizzle: all 16 qt-blocks of a bh share an XCD/L2.
  const int wg   = (blockIdx.x & 7) * 192 + (blockIdx.x >> 3);
  const int bh   = wg >> 4;               // 0..95
  const int qt   = wg & 15;
  const int b    = bh / HH, h = bh % HH;
  const int qbase = qt * 128 + wv * 32;

  // Q B-frags: B[k=d=q*8+i][n=query=ml]
  bf16x8 qf[2][2];
  #pragma unroll
  for (int mq = 0; mq < 2; ++mq)
    #pragma unroll
    for (int kt = 0; kt < 2; ++kt)
      qf[mq][kt] = *(const bf16x8*)(Qp + ((size_t)bh * NN + qbase + mq * 16 + ml) * DD + kt * 32 + q * 8);

  floatx4 O[2][4] = {};     // O^T: row d = dt*16+quad*4+r, col query = mq*16+ml
  floatx4 Osum[2] = {};
  f16x8 vone8 = {(_Float16)1.f, (_Float16)1.f, (_Float16)1.f, (_Float16)1.f,
                 (_Float16)1.f, (_Float16)1.f, (_Float16)1.f, (_Float16)1.f};

  const int kswz = ((lane & 7) ^ (lane >> 3)) * 8;        // K staging column
  const int vswz = ((lane & 15) ^ (lane >> 4)) * 8;       // V staging column (i even)
  const unsigned short* Kg = Kp + ((size_t)bh * NN + wv * 32 + (lane >> 3)) * DD + kswz;
  const unsigned short* Vg = Vt + ((size_t)bh * DD + wv * 16 + (lane >> 4)) * NN;
  unsigned short* Kl0 = &Ks[0][(wv * 32) * 64];
  unsigned short* Kl1 = &Ks[1][(wv * 32) * 64];
  unsigned short* Vl  = Vs + (wv * 16) * 128;

  // ---- prologue: stage K[0] -> Ks[0], V[0] -> Vs; bias tile 0; sz for tile 1
  #pragma unroll
  for (int i = 0; i < 4; ++i) {
    async_copy16(Kg + (size_t)(i * 8) * DD, Kl0 + i * 8 * 64);
    async_copy16(Vg + (size_t)(i * 4) * NN + (vswz ^ ((i & 1) << 5)), Vl + i * 4 * 128);
  }
  float szreg = 0.f;
  if (t < 128) {
    biasS[0][t] = log2f(sz[(size_t)b * NN + t]);
    szreg = sz[(size_t)b * NN + 128 + t];
  }
  __syncthreads();

  for (int jt = 0; jt < 16; ++jt) {
    const int cur = jt & 1;
    const int jn  = jt * 128 + 128;
    unsigned short* Kln = cur ? Kl0 : Kl1;

    // ---- top: issue K[t+1] async; publish bias[t+1] ----
    if (jt < 15) {
      #pragma unroll
      for (int i = 0; i < 4; ++i)
        async_copy16(Kg + (size_t)(jn + i * 8) * DD, Kln + i * 8 * 64);
      if (t < 128) {
        biasS[cur ^ 1][t] = log2f(szreg);             // value prefetched last iter
        int j2 = jn + 128; if (j2 + 128 > NN) j2 = NN - 128;
        szreg = sz[(size_t)b * NN + j2 + t];          // issue for tile jt+2
      }
    }

    // ---- S/exp software pipeline: MFMAs for nt issue while exp/cvt of
    //      nt-1 (independent) runs on the VALU pipe. ----
    f16x4 pf4[2][8];        // P for key nt, rows q*4..q*4+3 (2 VGPRs each)
    floatx4 Sp[2];
    auto emit_exp = [&](int pn) {
      floatx4 bv = *(const floatx4*)&biasS[cur][pn * 16 + q * 4];
      #pragma unroll
      for (int mq = 0; mq < 2; ++mq) {
        float e0 = __builtin_amdgcn_exp2f(fmaf(Sp[mq][0], SCALE2, bv[0]));
        float e1 = __builtin_amdgcn_exp2f(fmaf(Sp[mq][1], SCALE2, bv[1]));
        float e2 = __builtin_amdgcn_exp2f(fmaf(Sp[mq][2], SCALE2, bv[2]));
        float e3 = __builtin_amdgcn_exp2f(fmaf(Sp[mq][3], SCALE2, bv[3]));
        union { f16x2 h2[2]; f16x4 v; } pk;
        pk.h2[0] = cvt_pk(e0, e1);
        pk.h2[1] = cvt_pk(e2, e3);
        pf4[mq][pn] = pk.v;
      }
    };
    #pragma unroll
    for (int nt = 0; nt < 8; ++nt) {
      const int ch0 = (q ^ (ml & 7)) * 8;
      const int ch1 = ((4 + q) ^ (ml & 7)) * 8;
      bf16x8 kf0 = *(const bf16x8*)&Ks[cur][(nt * 16 + ml) * 64 + ch0];
      bf16x8 kf1 = *(const bf16x8*)&Ks[cur][(nt * 16 + ml) * 64 + ch1];
      floatx4 Sc[2];
      #pragma unroll
      for (int mq = 0; mq < 2; ++mq) {
        floatx4 a = {0.f, 0.f, 0.f, 0.f};
        a = __builtin_amdgcn_mfma_f32_16x16x32_bf16(kf0, qf[mq][0], a, 0, 0, 0);
        a = __builtin_amdgcn_mfma_f32_16x16x32_bf16(kf1, qf[mq][1], a, 0, 0, 0);
        Sc[mq] = a;
      }
      if (nt > 0) emit_exp(nt - 1);   // VALU work independent of in-flight MFMAs
      Sp[0] = Sc[0]; Sp[1] = Sc[1];
    }
    emit_exp(7);

    // K=32 f16 B-frags: pfw[tt] = concat(pf4[2tt], pf4[2tt+1]) — register-
    // pair concat, free after regalloc.
    f16x8 pfw[2][4];
    #pragma unroll
    for (int mq = 0; mq < 2; ++mq)
      #pragma unroll
      for (int tt = 0; tt < 4; ++tt)
        pfw[mq][tt] = __builtin_shufflevector(pf4[mq][2 * tt], pf4[mq][2 * tt + 1],
                                              0, 1, 2, 3, 4, 5, 6, 7);

    // barrier Y: drains V[t] (issued last iter, covered by this tile's
    // QK^T+exp and earlier) and K[t+1] (issued above); syncs before PV.
    __syncthreads();

    // ---- O^T += V^T P^T (K=32 f16 MFMA; vv f16x8 IS the K=32 A-frag) ----
    __builtin_amdgcn_s_setprio(1);
    #pragma unroll
    for (int dt = 0; dt < 4; ++dt) {
      #pragma unroll
      for (int tt = 0; tt < 4; ++tt) {
        const int ch = ((q * 4 + tt) ^ (ml & 7)) * 8;
        f16x8 vv = *(const f16x8*)&Vs[(dt * 16 + ml) * 128 + ch];
        #pragma unroll
        for (int mq = 0; mq < 2; ++mq)
          O[mq][dt] = __builtin_amdgcn_mfma_f32_16x16x32_f16(vv, pfw[mq][tt], O[mq][dt], 0, 0, 0);
      }
    }
    __builtin_amdgcn_s_setprio(0);

    // barrier X: all PV reads of Vs complete -> safe to restage Vs
    __syncthreads();

    // ---- issue V[t+1] async (covered by Osum + next tile's QK^T+exp) ----
    if (jt < 15) {
      #pragma unroll
      for (int i = 0; i < 4; ++i)
        async_copy16(Vg + (size_t)(i * 4) * NN + jn + (vswz ^ ((i & 1) << 5)), Vl + i * 4 * 128);
    }

    // ---- Osum += 1 * P^T (register-only; covers the V issue) ----
    __builtin_amdgcn_s_setprio(1);
    #pragma unroll
    for (int mq = 0; mq < 2; ++mq)
      #pragma unroll
      for (int tt = 0; tt < 4; ++tt)
        Osum[mq] = __builtin_amdgcn_mfma_f32_16x16x32_f16(vone8, pfw[mq][tt], Osum[mq], 0, 0, 0);
    __builtin_amdgcn_s_setprio(0);
  }

  // ---- epilogue: lane owns query = qbase+mq*16+ml, d = dt*16+quad*4+r ----
  #pragma unroll
  for (int mq = 0; mq < 2; ++mq) {
    const float linv = 1.0f / Osum[mq][0];
    const int query = qbase + mq * 16 + ml;
    #pragma unroll
    for (int dt = 0; dt < 4; ++dt) {
      union { unsigned short us[4]; unsigned long long u; } pk;
      #pragma unroll
      for (int r = 0; r < 4; ++r) pk.us[r] = f2bf(O[mq][dt][r] * linv);
      *(unsigned long long*)&attn_out[((size_t)b * NN + query) * CC + h * DD + dt * 16 + q * 4] = pk.u;
    }
  }
}

// ---------------------------------------------------------------------------
// k_mean[b,n,hd] = (1/H) sum_h K[b,h,n,hd]  — vectorized: 4 hd per thread.
// ---------------------------------------------------------------------------
__global__ void kmean_kernel(const unsigned short* __restrict__ Kp, float* __restrict__ o) {
  int idx = blockIdx.x * 256 + threadIdx.x;   // 262144 threads total
  int hd4 = (idx & 15) << 2;
  int n   = (idx >> 4) & (NN - 1);
  int b   = idx >> 15;
  float s0 = 0.f, s1 = 0.f, s2 = 0.f, s3 = 0.f;
  #pragma unroll
  for (int h = 0; h < HH; ++h) {
    ushort4 u = *(const ushort4*)&Kp[(((size_t)b * HH + h) * NN + n) * DD + hd4];
    s0 += bf2f(u.x); s1 += bf2f(u.y); s2 += bf2f(u.z); s3 += bf2f(u.w);
  }
  float4 r;
  r.x = s0 * (1.0f / 12.0f); r.y = s1 * (1.0f / 12.0f);
  r.z = s2 * (1.0f / 12.0f); r.w = s3 * (1.0f / 12.0f);
  *(float4*)&o[(size_t)idx * 4] = r;
}

extern "C" void kernel_launch(void* const* d_in, const int* in_sizes, int n_in,
                              void* d_out, int out_size, void* d_ws, size_t ws_size,
                              hipStream_t stream) {
  const float* x   = (const float*)d_in[0];
  const float* sz  = (const float*)d_in[1];
  const float* q_w = (const float*)d_in[2];
  const float* q_b = (const float*)d_in[3];
  const float* k_w = (const float*)d_in[4];
  const float* k_b = (const float*)d_in[5];
  const float* v_w = (const float*)d_in[6];
  const float* v_b = (const float*)d_in[7];
  const float* o_w = (const float*)d_in[8];
  const float* o_b = (const float*)d_in[9];

  float* out0  = (float*)d_out;              // [B,N,C] f32
  float* outKm = out0 + (size_t)BNC;         // [B,N,HD] f32

  unsigned short* xb   = (unsigned short*)d_ws;              // bf16 x / later Aw
  unsigned short* wcat = xb + XN;                            // bf16 [2304][768]
  unsigned short* owb  = wcat + 3 * WN;                      // bf16 [768][768]
  float*          bcat = (float*)(owb + WN);                 // f32 [2304]
  unsigned short* Qw   = (unsigned short*)(bcat + 2304);     // bf16 [B,H,N,64]
  unsigned short* Kw   = Qw + BNC;                           // bf16 [B,H,N,64]
  unsigned short* Vtw  = Kw + BNC;                           // f16  [B,H,64,N] permuted
  unsigned short* Aw   = xb;                                 // alias

  dim3 tb(256, 1, 1);
  convert_kernel<<<dim3(14595), tb, 0, stream>>>(x, q_w, k_w, v_w, o_w, q_b, k_b, v_b,
                                                 xb, wcat, owb, bcat);
  gemm_m97<0><<<dim3(128, 18), tb, 0, stream>>>(xb, wcat, bcat, Qw, Kw, Vtw, nullptr);
  attn_kernel<<<dim3(BB * HH * 16), tb, 0, stream>>>(Qw, Kw, Vtw, sz, Aw);
  gemm_m97<1><<<dim3(128, 6), tb, 0, stream>>>(Aw, owb, o_b, nullptr, nullptr, nullptr, out0);
  kmean_kernel<<<dim3(1024), tb, 0, stream>>>(Kw, outKm);
}

// Round 14
// 327.545 us; speedup vs baseline: 2.1458x; 1.0282x over previous
//
#include <hip/hip_runtime.h>
#include <math.h>

constexpr int BB = 8, NN = 2048, CC = 768, HH = 12, DD = 64;
constexpr float SCALE2 = 0.18033688011112042f;   // 0.125 * log2(e)
constexpr long long BNC = (long long)BB * NN * CC;   // 12,582,912
constexpr long long WN  = 589824LL;                  // 768*768
constexpr long long XN  = BNC;                       // x element count

using bf16x8  = __attribute__((ext_vector_type(8))) __bf16;
using floatx4 = __attribute__((ext_vector_type(4))) float;
using f16x4   = __attribute__((ext_vector_type(4))) _Float16;
using f16x8   = __attribute__((ext_vector_type(8))) _Float16;
using f16x2   = __attribute__((ext_vector_type(2))) _Float16;

static __device__ __forceinline__ unsigned short f2bf(float x) {
  unsigned u = __builtin_bit_cast(unsigned, x);
  u += 0x7fffu + ((u >> 16) & 1u);
  return (unsigned short)(u >> 16);
}
static __device__ __forceinline__ float bf2f(unsigned short s) {
  unsigned u = ((unsigned)s) << 16;
  return __builtin_bit_cast(float, u);
}

// v_cvt_pkrtz_f16_f32 wrapper (R9 fix: builtin returns __fp16-vector).
static __device__ __forceinline__ f16x2 cvt_pk(float a, float b) {
  return __builtin_bit_cast(f16x2, __builtin_amdgcn_cvt_pkrtz(a, b));
}

static __device__ __forceinline__ void async_copy16(const unsigned short* g, unsigned short* l) {
  __builtin_amdgcn_global_load_lds(
      (const __attribute__((address_space(1))) unsigned int*)g,
      (__attribute__((address_space(3))) unsigned int*)l, 16, 0, 0);
}

// ---------------------------------------------------------------------------
// Convert pass: x -> bf16, wcat = concat(qw,kw,vw) bf16, owb = ow bf16,
// bcat = concat(qb,kb,vb) f32.
// ---------------------------------------------------------------------------
__global__ void convert_kernel(const float* __restrict__ x,
    const float* __restrict__ qw, const float* __restrict__ kw,
    const float* __restrict__ vw, const float* __restrict__ ow,
    const float* __restrict__ qb, const float* __restrict__ kb,
    const float* __restrict__ vb,
    unsigned short* __restrict__ xb, unsigned short* __restrict__ wcat,
    unsigned short* __restrict__ owb, float* __restrict__ bcat) {
  const long long gid = (long long)blockIdx.x * 256 + threadIdx.x;
  const long long off = gid * 4;
  if (off < XN + 4 * WN) {
    const float* s; unsigned short* d;
    if (off < XN)              { s = x  + off;                 d = xb   + off; }
    else if (off < XN + WN)    { s = qw + (off - XN);          d = wcat + (off - XN); }
    else if (off < XN + 2*WN)  { s = kw + (off - XN - WN);     d = wcat + (off - XN); }
    else if (off < XN + 3*WN)  { s = vw + (off - XN - 2*WN);   d = wcat + (off - XN); }
    else                       { s = ow + (off - XN - 3*WN);   d = owb  + (off - XN - 3*WN); }
    floatx4 v = *(const floatx4*)s;
    union { unsigned short us[4]; unsigned long long u; } pk;
    pk.us[0] = f2bf(v.x); pk.us[1] = f2bf(v.y); pk.us[2] = f2bf(v.z); pk.us[3] = f2bf(v.w);
    *(unsigned long long*)d = pk.u;
  } else {
    long long r = gid - (XN + 4 * WN) / 4;
    if (r < 576) {
      long long o2 = r * 4;
      const float* s = (o2 < 768) ? qb + o2 : (o2 < 1536) ? kb + (o2 - 768) : vb + (o2 - 1536);
      *(floatx4*)(bcat + o2) = *(const floatx4*)s;
    }
  }
}

// ---------------------------------------------------------------------------
// m97-style GEMM with XOR-swizzled LDS (128x128, 256 threads, (256,3) —
// FINAL: BN=256 tested in R12, neutral-to-worse; 128^2's 3 blocks/CU wins).
// OUT_MODE 0: QKV split (y:0-5 Q bf16, 6-11 K bf16, 12-17 V^T f16 PERMUTED
// per 128-key chunk: pos = quad*32 + nt*4 + r). OUT_MODE 1: f32 out.
// ---------------------------------------------------------------------------
template<int OUT_MODE>
__global__ __launch_bounds__(256, 3)
void gemm_m97(const unsigned short* __restrict__ A,
              const unsigned short* __restrict__ Bw,
              const float* __restrict__ bias,
              unsigned short* __restrict__ Qo,
              unsigned short* __restrict__ Ko,
              unsigned short* __restrict__ Vo,
              float* __restrict__ Fo) {
  __shared__ __align__(16) unsigned short As[128 * 64];
  __shared__ __align__(16) unsigned short Bs[128 * 64];
  const int t    = threadIdx.x;
  const int lane = t & 63;
  const int wv   = t >> 6;
  const int q    = lane >> 4;
  const int ml   = lane & 15;
  const int wm   = wv >> 1, wn = wv & 1;
  const int m0   = blockIdx.x * 128;
  const int n0   = blockIdx.y * 128;
  const int scol = ((lane & 7) ^ (lane >> 3)) * 8;   // swizzled source column

  const unsigned short* Ag = A  + (size_t)(m0 + wv * 32 + (lane >> 3)) * CC + scol;
  const unsigned short* Bg = Bw + (size_t)(n0 + wv * 32 + (lane >> 3)) * CC + scol;
  unsigned short* Al = As + (wv * 32) * 64;
  unsigned short* Bl = Bs + (wv * 32) * 64;

  floatx4 acc[4][4] = {};

  for (int k0 = 0; k0 < CC; k0 += 64) {
    #pragma unroll
    for (int i = 0; i < 4; ++i) {
      async_copy16(Ag + (size_t)i * 8 * CC + k0, Al + i * 8 * 64);
      async_copy16(Bg + (size_t)i * 8 * CC + k0, Bl + i * 8 * 64);
    }
    __syncthreads();
    #pragma unroll
    for (int kk = 0; kk < 2; ++kk) {
      bf16x8 af[4], bg[4];
      #pragma unroll
      for (int mt = 0; mt < 4; ++mt) {
        const int ch = ((kk * 4 + q) ^ (ml & 7)) * 8;
        af[mt] = *(const bf16x8*)&As[(wm * 64 + mt * 16 + ml) * 64 + ch];
      }
      #pragma unroll
      for (int nt = 0; nt < 4; ++nt) {
        const int ch = ((kk * 4 + q) ^ (ml & 7)) * 8;
        bg[nt] = *(const bf16x8*)&Bs[(wn * 64 + nt * 16 + ml) * 64 + ch];
      }
      #pragma unroll
      for (int mt = 0; mt < 4; ++mt)
        #pragma unroll
        for (int nt = 0; nt < 4; ++nt)
          acc[mt][nt] = __builtin_amdgcn_mfma_f32_16x16x32_bf16(af[mt], bg[nt], acc[mt][nt], 0, 0, 0);
    }
    __syncthreads();
  }

  #pragma unroll
  for (int nt = 0; nt < 4; ++nt) {
    const int col = n0 + wn * 64 + nt * 16 + ml;
    const float bv = bias[col];
    #pragma unroll
    for (int mt = 0; mt < 4; ++mt) {
      const int mbase = m0 + wm * 64 + mt * 16 + q * 4;
      if (OUT_MODE == 1) {
        #pragma unroll
        for (int r = 0; r < 4; ++r)
          Fo[(size_t)(mbase + r) * CC + col] = acc[mt][nt][r] + bv;
      } else {
        const int region = blockIdx.y / 6;            // 0=Q,1=K,2=V
        const int lc = col - region * CC;
        const int h = lc >> 6, hd = lc & 63;
        const int bidx = mbase >> 11;
        if (region == 2) {
          // permuted V^T f16: n' = (n&~127) + quad_*32 + nt_*4 + r
          const int nloc  = mbase & (NN - 1);
          const int pbase = (nloc & ~127) + (((nloc >> 2) & 3) << 5) + (((nloc >> 4) & 7) << 2);
          union { _Float16 h4[4]; unsigned long long u; } pk;
          #pragma unroll
          for (int r = 0; r < 4; ++r) pk.h4[r] = (_Float16)(acc[mt][nt][r] + bv);
          *(unsigned long long*)&Vo[((size_t)(bidx * HH + h) * DD + hd) * NN + pbase] = pk.u;
        } else {
          const int n = mbase & (NN - 1);
          unsigned short* o = (region == 0) ? Qo : Ko;
          #pragma unroll
          for (int r = 0; r < 4; ++r)
            o[((size_t)(bidx * HH + h) * NN + n + r) * DD + hd] = f2bf(acc[mt][nt][r] + bv);
        }
      }
    }
  }
}

// ---------------------------------------------------------------------------
// Flash attention v15 = v14 + (a) launch_bounds(256,3) and (b) deferred
// exp(7) across barrier Y with tt-outer PV.
// R13 post-mortem: v14's S/exp pipeline won (-12.5us, VGPR 100->80, Occ
// 20->27.4%). (a) VGPR 80 <= 84 now FITS the arg=3 cap that guarantees 3
// blocks/CU (R8: Occ 30.5%) — v10/v12 couldn't take this. (b) the last exp
// slice (~100 VALU cyc) was exposed before barrier Y; moved after it, with
// PV reordered tt-outer so its consumer pfw[3] is needed after 24 of 32
// MFMAs -> scheduler hides it; waves also reach the barrier sooner.
// ---------------------------------------------------------------------------
__global__ __launch_bounds__(256, 3)
void attn_kernel(const unsigned short* __restrict__ Qp,
                 const unsigned short* __restrict__ Kp,
                 const unsigned short* __restrict__ Vt,   // f16, permuted
                 const float* __restrict__ sz,
                 unsigned short* __restrict__ attn_out) {
  __shared__ __align__(16) unsigned short Ks[2][128 * 64];   // bf16, swizzled (32KB)
  __shared__ __align__(16) unsigned short Vs[64 * 128];      // f16, permuted+swizzled (16KB)
  __shared__ __align__(16) float biasS[2][128];

  const int t    = threadIdx.x;
  const int lane = t & 63;
  const int wv   = t >> 6;
  const int q    = lane >> 4;
  const int ml   = lane & 15;
  // XCD swizzle: all 16 qt-blocks of a bh share an XCD/L2.
  const int wg   = (blockIdx.x & 7) * 192 + (blockIdx.x >> 3);
  const int bh   = wg >> 4;               // 0..95
  const int qt   = wg & 15;
  const int b    = bh / HH, h = bh % HH;
  const int qbase = qt * 128 + wv * 32;

  // Q B-frags: B[k=d=q*8+i][n=query=ml]
  bf16x8 qf[2][2];
  #pragma unroll
  for (int mq = 0; mq < 2; ++mq)
    #pragma unroll
    for (int kt = 0; kt < 2; ++kt)
      qf[mq][kt] = *(const bf16x8*)(Qp + ((size_t)bh * NN + qbase + mq * 16 + ml) * DD + kt * 32 + q * 8);

  floatx4 O[2][4] = {};     // O^T: row d = dt*16+quad*4+r, col query = mq*16+ml
  floatx4 Osum[2] = {};
  f16x8 vone8 = {(_Float16)1.f, (_Float16)1.f, (_Float16)1.f, (_Float16)1.f,
                 (_Float16)1.f, (_Float16)1.f, (_Float16)1.f, (_Float16)1.f};

  const int kswz = ((lane & 7) ^ (lane >> 3)) * 8;        // K staging column
  const int vswz = ((lane & 15) ^ (lane >> 4)) * 8;       // V staging column (i even)
  const unsigned short* Kg = Kp + ((size_t)bh * NN + wv * 32 + (lane >> 3)) * DD + kswz;
  const unsigned short* Vg = Vt + ((size_t)bh * DD + wv * 16 + (lane >> 4)) * NN;
  unsigned short* Kl0 = &Ks[0][(wv * 32) * 64];
  unsigned short* Kl1 = &Ks[1][(wv * 32) * 64];
  unsigned short* Vl  = Vs + (wv * 16) * 128;

  // ---- prologue: stage K[0] -> Ks[0], V[0] -> Vs; bias tile 0; sz for tile 1
  #pragma unroll
  for (int i = 0; i < 4; ++i) {
    async_copy16(Kg + (size_t)(i * 8) * DD, Kl0 + i * 8 * 64);
    async_copy16(Vg + (size_t)(i * 4) * NN + (vswz ^ ((i & 1) << 5)), Vl + i * 4 * 128);
  }
  float szreg = 0.f;
  if (t < 128) {
    biasS[0][t] = log2f(sz[(size_t)b * NN + t]);
    szreg = sz[(size_t)b * NN + 128 + t];
  }
  __syncthreads();

  for (int jt = 0; jt < 16; ++jt) {
    const int cur = jt & 1;
    const int jn  = jt * 128 + 128;
    unsigned short* Kln = cur ? Kl0 : Kl1;

    // ---- top: issue K[t+1] async; publish bias[t+1] ----
    if (jt < 15) {
      #pragma unroll
      for (int i = 0; i < 4; ++i)
        async_copy16(Kg + (size_t)(jn + i * 8) * DD, Kln + i * 8 * 64);
      if (t < 128) {
        biasS[cur ^ 1][t] = log2f(szreg);             // value prefetched last iter
        int j2 = jn + 128; if (j2 + 128 > NN) j2 = NN - 128;
        szreg = sz[(size_t)b * NN + j2 + t];          // issue for tile jt+2
      }
    }

    // ---- S/exp software pipeline: MFMAs for nt issue while exp/cvt of
    //      nt-1 (independent) runs on the VALU pipe. exp(7) is deferred
    //      across barrier Y (S lives in registers). ----
    f16x4 pf4[2][8];        // P for key nt, rows q*4..q*4+3 (2 VGPRs each)
    floatx4 Sp[2];
    auto emit_exp = [&](int pn) {
      floatx4 bv = *(const floatx4*)&biasS[cur][pn * 16 + q * 4];
      #pragma unroll
      for (int mq = 0; mq < 2; ++mq) {
        float e0 = __builtin_amdgcn_exp2f(fmaf(Sp[mq][0], SCALE2, bv[0]));
        float e1 = __builtin_amdgcn_exp2f(fmaf(Sp[mq][1], SCALE2, bv[1]));
        float e2 = __builtin_amdgcn_exp2f(fmaf(Sp[mq][2], SCALE2, bv[2]));
        float e3 = __builtin_amdgcn_exp2f(fmaf(Sp[mq][3], SCALE2, bv[3]));
        union { f16x2 h2[2]; f16x4 v; } pk;
        pk.h2[0] = cvt_pk(e0, e1);
        pk.h2[1] = cvt_pk(e2, e3);
        pf4[mq][pn] = pk.v;
      }
    };
    #pragma unroll
    for (int nt = 0; nt < 8; ++nt) {
      const int ch0 = (q ^ (ml & 7)) * 8;
      const int ch1 = ((4 + q) ^ (ml & 7)) * 8;
      bf16x8 kf0 = *(const bf16x8*)&Ks[cur][(nt * 16 + ml) * 64 + ch0];
      bf16x8 kf1 = *(const bf16x8*)&Ks[cur][(nt * 16 + ml) * 64 + ch1];
      floatx4 Sc[2];
      #pragma unroll
      for (int mq = 0; mq < 2; ++mq) {
        floatx4 a = {0.f, 0.f, 0.f, 0.f};
        a = __builtin_amdgcn_mfma_f32_16x16x32_bf16(kf0, qf[mq][0], a, 0, 0, 0);
        a = __builtin_amdgcn_mfma_f32_16x16x32_bf16(kf1, qf[mq][1], a, 0, 0, 0);
        Sc[mq] = a;
      }
      if (nt > 0) emit_exp(nt - 1);   // VALU work independent of in-flight MFMAs
      Sp[0] = Sc[0]; Sp[1] = Sc[1];
    }

    // barrier Y: drains V[t] (issued last iter, covered by this tile's
    // QK^T+exp and earlier) and K[t+1] (issued above); syncs before PV.
    __syncthreads();

    // deferred exp(7): only consumer is pfw[3], needed after 24 of 32 PV
    // MFMAs (tt-outer order) -> scheduler hides it under MFMA issue.
    emit_exp(7);

    // ---- O^T += V^T P^T (K=32 f16 MFMA; vv f16x8 IS the K=32 A-frag);
    //      tt outer so pf4[6],pf4[7] are consumed last. ----
    f16x8 pfw[2][4];
    __builtin_amdgcn_s_setprio(1);
    #pragma unroll
    for (int tt = 0; tt < 4; ++tt) {
      #pragma unroll
      for (int mq = 0; mq < 2; ++mq)
        pfw[mq][tt] = __builtin_shufflevector(pf4[mq][2 * tt], pf4[mq][2 * tt + 1],
                                              0, 1, 2, 3, 4, 5, 6, 7);
      #pragma unroll
      for (int dt = 0; dt < 4; ++dt) {
        const int ch = ((q * 4 + tt) ^ (ml & 7)) * 8;
        f16x8 vv = *(const f16x8*)&Vs[(dt * 16 + ml) * 128 + ch];
        #pragma unroll
        for (int mq = 0; mq < 2; ++mq)
          O[mq][dt] = __builtin_amdgcn_mfma_f32_16x16x32_f16(vv, pfw[mq][tt], O[mq][dt], 0, 0, 0);
      }
    }
    __builtin_amdgcn_s_setprio(0);

    // barrier X: all PV reads of Vs complete -> safe to restage Vs
    __syncthreads();

    // ---- issue V[t+1] async (covered by Osum + next tile's QK^T+exp) ----
    if (jt < 15) {
      #pragma unroll
      for (int i = 0; i < 4; ++i)
        async_copy16(Vg + (size_t)(i * 4) * NN + jn + (vswz ^ ((i & 1) << 5)), Vl + i * 4 * 128);
    }

    // ---- Osum += 1 * P^T (register-only; covers the V issue) ----
    __builtin_amdgcn_s_setprio(1);
    #pragma unroll
    for (int mq = 0; mq < 2; ++mq)
      #pragma unroll
      for (int tt = 0; tt < 4; ++tt)
        Osum[mq] = __builtin_amdgcn_mfma_f32_16x16x32_f16(vone8, pfw[mq][tt], Osum[mq], 0, 0, 0);
    __builtin_amdgcn_s_setprio(0);
  }

  // ---- epilogue: lane owns query = qbase+mq*16+ml, d = dt*16+quad*4+r ----
  #pragma unroll
  for (int mq = 0; mq < 2; ++mq) {
    const float linv = 1.0f / Osum[mq][0];
    const int query = qbase + mq * 16 + ml;
    #pragma unroll
    for (int dt = 0; dt < 4; ++dt) {
      union { unsigned short us[4]; unsigned long long u; } pk;
      #pragma unroll
      for (int r = 0; r < 4; ++r) pk.us[r] = f2bf(O[mq][dt][r] * linv);
      *(unsigned long long*)&attn_out[((size_t)b * NN + query) * CC + h * DD + dt * 16 + q * 4] = pk.u;
    }
  }
}

// ---------------------------------------------------------------------------
// k_mean[b,n,hd] = (1/H) sum_h K[b,h,n,hd]  — vectorized: 4 hd per thread.
// ---------------------------------------------------------------------------
__global__ void kmean_kernel(const unsigned short* __restrict__ Kp, float* __restrict__ o) {
  int idx = blockIdx.x * 256 + threadIdx.x;   // 262144 threads total
  int hd4 = (idx & 15) << 2;
  int n   = (idx >> 4) & (NN - 1);
  int b   = idx >> 15;
  float s0 = 0.f, s1 = 0.f, s2 = 0.f, s3 = 0.f;
  #pragma unroll
  for (int h = 0; h < HH; ++h) {
    ushort4 u = *(const ushort4*)&Kp[(((size_t)b * HH + h) * NN + n) * DD + hd4];
    s0 += bf2f(u.x); s1 += bf2f(u.y); s2 += bf2f(u.z); s3 += bf2f(u.w);
  }
  float4 r;
  r.x = s0 * (1.0f / 12.0f); r.y = s1 * (1.0f / 12.0f);
  r.z = s2 * (1.0f / 12.0f); r.w = s3 * (1.0f / 12.0f);
  *(float4*)&o[(size_t)idx * 4] = r;
}

extern "C" void kernel_launch(void* const* d_in, const int* in_sizes, int n_in,
                              void* d_out, int out_size, void* d_ws, size_t ws_size,
                              hipStream_t stream) {
  const float* x   = (const float*)d_in[0];
  const float* sz  = (const float*)d_in[1];
  const float* q_w = (const float*)d_in[2];
  const float* q_b = (const float*)d_in[3];
  const float* k_w = (const float*)d_in[4];
  const float* k_b = (const float*)d_in[5];
  const float* v_w = (const float*)d_in[6];
  const float* v_b = (const float*)d_in[7];
  const float* o_w = (const float*)d_in[8];
  const float* o_b = (const float*)d_in[9];

  float* out0  = (float*)d_out;              // [B,N,C] f32
  float* outKm = out0 + (size_t)BNC;         // [B,N,HD] f32

  unsigned short* xb   = (unsigned short*)d_ws;              // bf16 x / later Aw
  unsigned short* wcat = xb + XN;                            // bf16 [2304][768]
  unsigned short* owb  = wcat + 3 * WN;                      // bf16 [768][768]
  float*          bcat = (float*)(owb + WN);                 // f32 [2304]
  unsigned short* Qw   = (unsigned short*)(bcat + 2304);     // bf16 [B,H,N,64]
  unsigned short* Kw   = Qw + BNC;                           // bf16 [B,H,N,64]
  unsigned short* Vtw  = Kw + BNC;                           // f16  [B,H,64,N] permuted
  unsigned short* Aw   = xb;                                 // alias

  dim3 tb(256, 1, 1);
  convert_kernel<<<dim3(14595), tb, 0, stream>>>(x, q_w, k_w, v_w, o_w, q_b, k_b, v_b,
                                                 xb, wcat, owb, bcat);
  gemm_m97<0><<<dim3(128, 18), tb, 0, stream>>>(xb, wcat, bcat, Qw, Kw, Vtw, nullptr);
  attn_kernel<<<dim3(BB * HH * 16), tb, 0, stream>>>(Qw, Kw, Vtw, sz, Aw);
  gemm_m97<1><<<dim3(128, 6), tb, 0, stream>>>(Aw, owb, o_b, nullptr, nullptr, nullptr, out0);
  kmean_kernel<<<dim3(1024), tb, 0, stream>>>(Kw, outKm);
}

// Round 15
// 325.786 us; speedup vs baseline: 2.1574x; 1.0054x over previous
//
#include <hip/hip_runtime.h>
#include <math.h>

constexpr int BB = 8, NN = 2048, CC = 768, HH = 12, DD = 64;
constexpr float SCALE2 = 0.18033688011112042f;   // 0.125 * log2(e)
constexpr long long BNC = (long long)BB * NN * CC;   // 12,582,912
constexpr long long WN  = 589824LL;                  // 768*768
constexpr long long XN  = BNC;                       // x element count

using bf16x8  = __attribute__((ext_vector_type(8))) __bf16;
using floatx4 = __attribute__((ext_vector_type(4))) float;
using f16x4   = __attribute__((ext_vector_type(4))) _Float16;
using f16x8   = __attribute__((ext_vector_type(8))) _Float16;
using f16x2   = __attribute__((ext_vector_type(2))) _Float16;

static __device__ __forceinline__ unsigned short f2bf(float x) {
  unsigned u = __builtin_bit_cast(unsigned, x);
  u += 0x7fffu + ((u >> 16) & 1u);
  return (unsigned short)(u >> 16);
}
static __device__ __forceinline__ float bf2f(unsigned short s) {
  unsigned u = ((unsigned)s) << 16;
  return __builtin_bit_cast(float, u);
}

// v_cvt_pkrtz_f16_f32 wrapper (R9 fix: builtin returns __fp16-vector).
static __device__ __forceinline__ f16x2 cvt_pk(float a, float b) {
  return __builtin_bit_cast(f16x2, __builtin_amdgcn_cvt_pkrtz(a, b));
}

static __device__ __forceinline__ void async_copy16(const unsigned short* g, unsigned short* l) {
  __builtin_amdgcn_global_load_lds(
      (const __attribute__((address_space(1))) unsigned int*)g,
      (__attribute__((address_space(3))) unsigned int*)l, 16, 0, 0);
}

// ---------------------------------------------------------------------------
// Convert pass: x -> bf16, wcat = concat(qw,kw,vw) bf16, owb = ow bf16,
// bcat = concat(qb,kb,vb) f32.
// ---------------------------------------------------------------------------
__global__ void convert_kernel(const float* __restrict__ x,
    const float* __restrict__ qw, const float* __restrict__ kw,
    const float* __restrict__ vw, const float* __restrict__ ow,
    const float* __restrict__ qb, const float* __restrict__ kb,
    const float* __restrict__ vb,
    unsigned short* __restrict__ xb, unsigned short* __restrict__ wcat,
    unsigned short* __restrict__ owb, float* __restrict__ bcat) {
  const long long gid = (long long)blockIdx.x * 256 + threadIdx.x;
  const long long off = gid * 4;
  if (off < XN + 4 * WN) {
    const float* s; unsigned short* d;
    if (off < XN)              { s = x  + off;                 d = xb   + off; }
    else if (off < XN + WN)    { s = qw + (off - XN);          d = wcat + (off - XN); }
    else if (off < XN + 2*WN)  { s = kw + (off - XN - WN);     d = wcat + (off - XN); }
    else if (off < XN + 3*WN)  { s = vw + (off - XN - 2*WN);   d = wcat + (off - XN); }
    else                       { s = ow + (off - XN - 3*WN);   d = owb  + (off - XN - 3*WN); }
    floatx4 v = *(const floatx4*)s;
    union { unsigned short us[4]; unsigned long long u; } pk;
    pk.us[0] = f2bf(v.x); pk.us[1] = f2bf(v.y); pk.us[2] = f2bf(v.z); pk.us[3] = f2bf(v.w);
    *(unsigned long long*)d = pk.u;
  } else {
    long long r = gid - (XN + 4 * WN) / 4;
    if (r < 576) {
      long long o2 = r * 4;
      const float* s = (o2 < 768) ? qb + o2 : (o2 < 1536) ? kb + (o2 - 768) : vb + (o2 - 1536);
      *(floatx4*)(bcat + o2) = *(const floatx4*)s;
    }
  }
}

// ---------------------------------------------------------------------------
// m97-style GEMM with XOR-swizzled LDS (128x128, 256 threads, (256,3)).
// R15: LDS-TRANSPOSE EPILOGUE for Q/K regions — the old path issued 64
// scattered 2-byte global stores per thread (16K stores/block, sub-sector
// write combining). Now: acc -> bf16 -> 32KB LDS tile T[n][c] (32B-unit XOR
// swizzle vs bank collisions), barrier, then 8x fully-coalesced 16B stores
// per thread. V-region (u64 permuted) and OUT_MODE 1 paths unchanged.
// OUT_MODE 0: QKV split (y:0-5 Q bf16, 6-11 K bf16, 12-17 V^T f16 PERMUTED
// per 128-key chunk: pos = quad*32 + nt*4 + r). OUT_MODE 1: f32 out.
// ---------------------------------------------------------------------------
template<int OUT_MODE>
__global__ __launch_bounds__(256, 3)
void gemm_m97(const unsigned short* __restrict__ A,
              const unsigned short* __restrict__ Bw,
              const float* __restrict__ bias,
              unsigned short* __restrict__ Qo,
              unsigned short* __restrict__ Ko,
              unsigned short* __restrict__ Vo,
              float* __restrict__ Fo) {
  __shared__ __align__(16) unsigned short AB[2][128 * 64];   // As | Bs; reused as T[128][128]
  const int t    = threadIdx.x;
  const int lane = t & 63;
  const int wv   = t >> 6;
  const int q    = lane >> 4;
  const int ml   = lane & 15;
  const int wm   = wv >> 1, wn = wv & 1;
  const int m0   = blockIdx.x * 128;
  const int n0   = blockIdx.y * 128;
  const int scol = ((lane & 7) ^ (lane >> 3)) * 8;   // swizzled source column

  const unsigned short* Ag = A  + (size_t)(m0 + wv * 32 + (lane >> 3)) * CC + scol;
  const unsigned short* Bg = Bw + (size_t)(n0 + wv * 32 + (lane >> 3)) * CC + scol;
  unsigned short* Al = &AB[0][(wv * 32) * 64];
  unsigned short* Bl = &AB[1][(wv * 32) * 64];

  floatx4 acc[4][4] = {};

  for (int k0 = 0; k0 < CC; k0 += 64) {
    #pragma unroll
    for (int i = 0; i < 4; ++i) {
      async_copy16(Ag + (size_t)i * 8 * CC + k0, Al + i * 8 * 64);
      async_copy16(Bg + (size_t)i * 8 * CC + k0, Bl + i * 8 * 64);
    }
    __syncthreads();
    #pragma unroll
    for (int kk = 0; kk < 2; ++kk) {
      bf16x8 af[4], bg[4];
      #pragma unroll
      for (int mt = 0; mt < 4; ++mt) {
        const int ch = ((kk * 4 + q) ^ (ml & 7)) * 8;
        af[mt] = *(const bf16x8*)&AB[0][(wm * 64 + mt * 16 + ml) * 64 + ch];
      }
      #pragma unroll
      for (int nt = 0; nt < 4; ++nt) {
        const int ch = ((kk * 4 + q) ^ (ml & 7)) * 8;
        bg[nt] = *(const bf16x8*)&AB[1][(wn * 64 + nt * 16 + ml) * 64 + ch];
      }
      #pragma unroll
      for (int mt = 0; mt < 4; ++mt)
        #pragma unroll
        for (int nt = 0; nt < 4; ++nt)
          acc[mt][nt] = __builtin_amdgcn_mfma_f32_16x16x32_bf16(af[mt], bg[nt], acc[mt][nt], 0, 0, 0);
    }
    __syncthreads();
  }

  if (OUT_MODE == 0 && blockIdx.y < 12) {
    // ---- Q/K: LDS-transpose epilogue (coalesced 16B stores) ----
    char* Tb = (char*)&AB[0][0];   // 32KB = 128 rows x 256B, XOR-swizzled
    #pragma unroll
    for (int nt = 0; nt < 4; ++nt) {
      const int col = wn * 64 + nt * 16 + ml;
      const float bv = bias[n0 + col];
      #pragma unroll
      for (int mt = 0; mt < 4; ++mt) {
        const int rowb = wm * 64 + mt * 16 + q * 4;
        #pragma unroll
        for (int r = 0; r < 4; ++r) {
          const int row  = rowb + r;
          const int byte = row * 256 + ((col * 2) ^ (((row >> 2) & 7) << 5));
          *(unsigned short*)(Tb + byte) = f2bf(acc[mt][nt][r] + bv);
        }
      }
    }
    __syncthreads();
    const int region = blockIdx.y / 6;                 // 0=Q, 1=K (uniform)
    unsigned short* o = (region == 0) ? Qo : Ko;
    const int lc0 = n0 - region * CC;
    #pragma unroll
    for (int i = 0; i < 8; ++i) {
      const int id = i * 256 + t;
      const int n  = id >> 4;                          // local row 0..127
      const int cc = (id & 15) * 8;                    // local col, 8-wide
      const int byte = n * 256 + ((cc * 2) ^ (((n >> 2) & 7) << 5));
      uint4 v = *(const uint4*)(Tb + byte);
      const int gr = m0 + n;
      const int lc = lc0 + cc;
      const int h = lc >> 6, hd = lc & 63;
      *(uint4*)&o[((size_t)((gr >> 11) * HH + h) * NN + (gr & (NN - 1))) * DD + hd] = v;
    }
  } else {
    #pragma unroll
    for (int nt = 0; nt < 4; ++nt) {
      const int col = n0 + wn * 64 + nt * 16 + ml;
      const float bv = bias[col];
      #pragma unroll
      for (int mt = 0; mt < 4; ++mt) {
        const int mbase = m0 + wm * 64 + mt * 16 + q * 4;
        if (OUT_MODE == 1) {
          #pragma unroll
          for (int r = 0; r < 4; ++r)
            Fo[(size_t)(mbase + r) * CC + col] = acc[mt][nt][r] + bv;
        } else {
          // V region: permuted V^T f16, u64 stores (unchanged)
          const int lc = col - 2 * CC;
          const int h = lc >> 6, hd = lc & 63;
          const int bidx = mbase >> 11;
          const int nloc  = mbase & (NN - 1);
          const int pbase = (nloc & ~127) + (((nloc >> 2) & 3) << 5) + (((nloc >> 4) & 7) << 2);
          union { _Float16 h4[4]; unsigned long long u; } pk;
          #pragma unroll
          for (int r = 0; r < 4; ++r) pk.h4[r] = (_Float16)(acc[mt][nt][r] + bv);
          *(unsigned long long*)&Vo[((size_t)(bidx * HH + h) * DD + hd) * NN + pbase] = pk.u;
        }
      }
    }
  }
}

// ---------------------------------------------------------------------------
// Flash attention v15 (unchanged from R14 — attn at structural floor:
// MfmaUtil 43 + VALUBusy 52 = 95%, 122-123us).
// ---------------------------------------------------------------------------
__global__ __launch_bounds__(256, 3)
void attn_kernel(const unsigned short* __restrict__ Qp,
                 const unsigned short* __restrict__ Kp,
                 const unsigned short* __restrict__ Vt,   // f16, permuted
                 const float* __restrict__ sz,
                 unsigned short* __restrict__ attn_out) {
  __shared__ __align__(16) unsigned short Ks[2][128 * 64];   // bf16, swizzled (32KB)
  __shared__ __align__(16) unsigned short Vs[64 * 128];      // f16, permuted+swizzled (16KB)
  __shared__ __align__(16) float biasS[2][128];

  const int t    = threadIdx.x;
  const int lane = t & 63;
  const int wv   = t >> 6;
  const int q    = lane >> 4;
  const int ml   = lane & 15;
  // XCD swizzle: all 16 qt-blocks of a bh share an XCD/L2.
  const int wg   = (blockIdx.x & 7) * 192 + (blockIdx.x >> 3);
  const int bh   = wg >> 4;               // 0..95
  const int qt   = wg & 15;
  const int b    = bh / HH, h = bh % HH;
  const int qbase = qt * 128 + wv * 32;

  // Q B-frags: B[k=d=q*8+i][n=query=ml]
  bf16x8 qf[2][2];
  #pragma unroll
  for (int mq = 0; mq < 2; ++mq)
    #pragma unroll
    for (int kt = 0; kt < 2; ++kt)
      qf[mq][kt] = *(const bf16x8*)(Qp + ((size_t)bh * NN + qbase + mq * 16 + ml) * DD + kt * 32 + q * 8);

  floatx4 O[2][4] = {};     // O^T: row d = dt*16+quad*4+r, col query = mq*16+ml
  floatx4 Osum[2] = {};
  f16x8 vone8 = {(_Float16)1.f, (_Float16)1.f, (_Float16)1.f, (_Float16)1.f,
                 (_Float16)1.f, (_Float16)1.f, (_Float16)1.f, (_Float16)1.f};

  const int kswz = ((lane & 7) ^ (lane >> 3)) * 8;        // K staging column
  const int vswz = ((lane & 15) ^ (lane >> 4)) * 8;       // V staging column (i even)
  const unsigned short* Kg = Kp + ((size_t)bh * NN + wv * 32 + (lane >> 3)) * DD + kswz;
  const unsigned short* Vg = Vt + ((size_t)bh * DD + wv * 16 + (lane >> 4)) * NN;
  unsigned short* Kl0 = &Ks[0][(wv * 32) * 64];
  unsigned short* Kl1 = &Ks[1][(wv * 32) * 64];
  unsigned short* Vl  = Vs + (wv * 16) * 128;

  // ---- prologue: stage K[0] -> Ks[0], V[0] -> Vs; bias tile 0; sz for tile 1
  #pragma unroll
  for (int i = 0; i < 4; ++i) {
    async_copy16(Kg + (size_t)(i * 8) * DD, Kl0 + i * 8 * 64);
    async_copy16(Vg + (size_t)(i * 4) * NN + (vswz ^ ((i & 1) << 5)), Vl + i * 4 * 128);
  }
  float szreg = 0.f;
  if (t < 128) {
    biasS[0][t] = log2f(sz[(size_t)b * NN + t]);
    szreg = sz[(size_t)b * NN + 128 + t];
  }
  __syncthreads();

  for (int jt = 0; jt < 16; ++jt) {
    const int cur = jt & 1;
    const int jn  = jt * 128 + 128;
    unsigned short* Kln = cur ? Kl0 : Kl1;

    // ---- top: issue K[t+1] async; publish bias[t+1] ----
    if (jt < 15) {
      #pragma unroll
      for (int i = 0; i < 4; ++i)
        async_copy16(Kg + (size_t)(jn + i * 8) * DD, Kln + i * 8 * 64);
      if (t < 128) {
        biasS[cur ^ 1][t] = log2f(szreg);             // value prefetched last iter
        int j2 = jn + 128; if (j2 + 128 > NN) j2 = NN - 128;
        szreg = sz[(size_t)b * NN + j2 + t];          // issue for tile jt+2
      }
    }

    // ---- S/exp software pipeline: MFMAs for nt issue while exp/cvt of
    //      nt-1 (independent) runs on the VALU pipe. exp(7) is deferred
    //      across barrier Y (S lives in registers). ----
    f16x4 pf4[2][8];        // P for key nt, rows q*4..q*4+3 (2 VGPRs each)
    floatx4 Sp[2];
    auto emit_exp = [&](int pn) {
      floatx4 bv = *(const floatx4*)&biasS[cur][pn * 16 + q * 4];
      #pragma unroll
      for (int mq = 0; mq < 2; ++mq) {
        float e0 = __builtin_amdgcn_exp2f(fmaf(Sp[mq][0], SCALE2, bv[0]));
        float e1 = __builtin_amdgcn_exp2f(fmaf(Sp[mq][1], SCALE2, bv[1]));
        float e2 = __builtin_amdgcn_exp2f(fmaf(Sp[mq][2], SCALE2, bv[2]));
        float e3 = __builtin_amdgcn_exp2f(fmaf(Sp[mq][3], SCALE2, bv[3]));
        union { f16x2 h2[2]; f16x4 v; } pk;
        pk.h2[0] = cvt_pk(e0, e1);
        pk.h2[1] = cvt_pk(e2, e3);
        pf4[mq][pn] = pk.v;
      }
    };
    #pragma unroll
    for (int nt = 0; nt < 8; ++nt) {
      const int ch0 = (q ^ (ml & 7)) * 8;
      const int ch1 = ((4 + q) ^ (ml & 7)) * 8;
      bf16x8 kf0 = *(const bf16x8*)&Ks[cur][(nt * 16 + ml) * 64 + ch0];
      bf16x8 kf1 = *(const bf16x8*)&Ks[cur][(nt * 16 + ml) * 64 + ch1];
      floatx4 Sc[2];
      #pragma unroll
      for (int mq = 0; mq < 2; ++mq) {
        floatx4 a = {0.f, 0.f, 0.f, 0.f};
        a = __builtin_amdgcn_mfma_f32_16x16x32_bf16(kf0, qf[mq][0], a, 0, 0, 0);
        a = __builtin_amdgcn_mfma_f32_16x16x32_bf16(kf1, qf[mq][1], a, 0, 0, 0);
        Sc[mq] = a;
      }
      if (nt > 0) emit_exp(nt - 1);   // VALU work independent of in-flight MFMAs
      Sp[0] = Sc[0]; Sp[1] = Sc[1];
    }

    // barrier Y: drains V[t] (issued last iter, covered by this tile's
    // QK^T+exp and earlier) and K[t+1] (issued above); syncs before PV.
    __syncthreads();

    // deferred exp(7): only consumer is pfw[3], needed after 24 of 32 PV
    // MFMAs (tt-outer order) -> scheduler hides it under MFMA issue.
    emit_exp(7);

    // ---- O^T += V^T P^T (K=32 f16 MFMA; vv f16x8 IS the K=32 A-frag);
    //      tt outer so pf4[6],pf4[7] are consumed last. ----
    f16x8 pfw[2][4];
    __builtin_amdgcn_s_setprio(1);
    #pragma unroll
    for (int tt = 0; tt < 4; ++tt) {
      #pragma unroll
      for (int mq = 0; mq < 2; ++mq)
        pfw[mq][tt] = __builtin_shufflevector(pf4[mq][2 * tt], pf4[mq][2 * tt + 1],
                                              0, 1, 2, 3, 4, 5, 6, 7);
      #pragma unroll
      for (int dt = 0; dt < 4; ++dt) {
        const int ch = ((q * 4 + tt) ^ (ml & 7)) * 8;
        f16x8 vv = *(const f16x8*)&Vs[(dt * 16 + ml) * 128 + ch];
        #pragma unroll
        for (int mq = 0; mq < 2; ++mq)
          O[mq][dt] = __builtin_amdgcn_mfma_f32_16x16x32_f16(vv, pfw[mq][tt], O[mq][dt], 0, 0, 0);
      }
    }
    __builtin_amdgcn_s_setprio(0);

    // barrier X: all PV reads of Vs complete -> safe to restage Vs
    __syncthreads();

    // ---- issue V[t+1] async (covered by Osum + next tile's QK^T+exp) ----
    if (jt < 15) {
      #pragma unroll
      for (int i = 0; i < 4; ++i)
        async_copy16(Vg + (size_t)(i * 4) * NN + jn + (vswz ^ ((i & 1) << 5)), Vl + i * 4 * 128);
    }

    // ---- Osum += 1 * P^T (register-only; covers the V issue) ----
    __builtin_amdgcn_s_setprio(1);
    #pragma unroll
    for (int mq = 0; mq < 2; ++mq)
      #pragma unroll
      for (int tt = 0; tt < 4; ++tt)
        Osum[mq] = __builtin_amdgcn_mfma_f32_16x16x32_f16(vone8, pfw[mq][tt], Osum[mq], 0, 0, 0);
    __builtin_amdgcn_s_setprio(0);
  }

  // ---- epilogue: lane owns query = qbase+mq*16+ml, d = dt*16+quad*4+r ----
  #pragma unroll
  for (int mq = 0; mq < 2; ++mq) {
    const float linv = 1.0f / Osum[mq][0];
    const int query = qbase + mq * 16 + ml;
    #pragma unroll
    for (int dt = 0; dt < 4; ++dt) {
      union { unsigned short us[4]; unsigned long long u; } pk;
      #pragma unroll
      for (int r = 0; r < 4; ++r) pk.us[r] = f2bf(O[mq][dt][r] * linv);
      *(unsigned long long*)&attn_out[((size_t)b * NN + query) * CC + h * DD + dt * 16 + q * 4] = pk.u;
    }
  }
}

// ---------------------------------------------------------------------------
// k_mean[b,n,hd] = (1/H) sum_h K[b,h,n,hd]  — vectorized: 4 hd per thread.
// ---------------------------------------------------------------------------
__global__ void kmean_kernel(const unsigned short* __restrict__ Kp, float* __restrict__ o) {
  int idx = blockIdx.x * 256 + threadIdx.x;   // 262144 threads total
  int hd4 = (idx & 15) << 2;
  int n   = (idx >> 4) & (NN - 1);
  int b   = idx >> 15;
  float s0 = 0.f, s1 = 0.f, s2 = 0.f, s3 = 0.f;
  #pragma unroll
  for (int h = 0; h < HH; ++h) {
    ushort4 u = *(const ushort4*)&Kp[(((size_t)b * HH + h) * NN + n) * DD + hd4];
    s0 += bf2f(u.x); s1 += bf2f(u.y); s2 += bf2f(u.z); s3 += bf2f(u.w);
  }
  float4 r;
  r.x = s0 * (1.0f / 12.0f); r.y = s1 * (1.0f / 12.0f);
  r.z = s2 * (1.0f / 12.0f); r.w = s3 * (1.0f / 12.0f);
  *(float4*)&o[(size_t)idx * 4] = r;
}

extern "C" void kernel_launch(void* const* d_in, const int* in_sizes, int n_in,
                              void* d_out, int out_size, void* d_ws, size_t ws_size,
                              hipStream_t stream) {
  const float* x   = (const float*)d_in[0];
  const float* sz  = (const float*)d_in[1];
  const float* q_w = (const float*)d_in[2];
  const float* q_b = (const float*)d_in[3];
  const float* k_w = (const float*)d_in[4];
  const float* k_b = (const float*)d_in[5];
  const float* v_w = (const float*)d_in[6];
  const float* v_b = (const float*)d_in[7];
  const float* o_w = (const float*)d_in[8];
  const float* o_b = (const float*)d_in[9];

  float* out0  = (float*)d_out;              // [B,N,C] f32
  float* outKm = out0 + (size_t)BNC;         // [B,N,HD] f32

  unsigned short* xb   = (unsigned short*)d_ws;              // bf16 x / later Aw
  unsigned short* wcat = xb + XN;                            // bf16 [2304][768]
  unsigned short* owb  = wcat + 3 * WN;                      // bf16 [768][768]
  float*          bcat = (float*)(owb + WN);                 // f32 [2304]
  unsigned short* Qw   = (unsigned short*)(bcat + 2304);     // bf16 [B,H,N,64]
  unsigned short* Kw   = Qw + BNC;                           // bf16 [B,H,N,64]
  unsigned short* Vtw  = Kw + BNC;                           // f16  [B,H,64,N] permuted
  unsigned short* Aw   = xb;                                 // alias

  dim3 tb(256, 1, 1);
  convert_kernel<<<dim3(14595), tb, 0, stream>>>(x, q_w, k_w, v_w, o_w, q_b, k_b, v_b,
                                                 xb, wcat, owb, bcat);
  gemm_m97<0><<<dim3(128, 18), tb, 0, stream>>>(xb, wcat, bcat, Qw, Kw, Vtw, nullptr);
  attn_kernel<<<dim3(BB * HH * 16), tb, 0, stream>>>(Qw, Kw, Vtw, sz, Aw);
  gemm_m97<1><<<dim3(128, 6), tb, 0, stream>>>(Aw, owb, o_b, nullptr, nullptr, nullptr, out0);
  kmean_kernel<<<dim3(1024), tb, 0, stream>>>(Kw, outKm);
}